// Round 3
// baseline (7397.897 us; speedup 1.0000x reference)
//
#include <hip/hip_runtime.h>
#include <math.h>

// DRL4TSP decode: B=512, F=2, N=128, H=256, 128 steps.
// One workgroup (512 thr) owns 2 batch elems; all 128 steps in-kernel.
// R3: __launch_bounds__(512, 1). R2's default bounds made the compiler cap
// VGPRs at 128 and SPILL (WRITE_SIZE 427MB of scratch, which thrashed the
// per-XCD L2 and knocked the 1.3MB weight working set out of residency ->
// FETCH_SIZE 10.5GB). Grid is 256 blocks on 256 CUs = 1 block/CU, so the
// 128-VGPR cap bought zero occupancy. (512,1) allows 256 VGPR/thread.

#define NB 512
#define NF 2
#define NN 128
#define NH 256
#define NH3 768

// ws layout (floats):
//   0     : Mgi[768] float2   (W_ih·Wdec, 2 cols interleaved)
//   1536  : cgi[768]          (W_ih·bdec + b_ih)
//   2304  : cA[256] float4    (2*A_s0, 2*A_s1, 2*A_d1, va)
//   3328  : a0[256]           (2*(Wa_s·bs + Wa_d·(20*Wd0+bd)))
//   3584  : cP[256] float4    (2*P_s0, 2*P_s1, vp, 0)
//   5376  : WaH[256*256]      (2*Wa[:,2H:3H] row-major)
//   70912 : cP2[256] float4   (2*PC0, 2*PC1, 2*pb, 0)
// x2 pre-scaling folds tanh(x)=1-2/(1+exp(2x)) exactly.

__device__ __forceinline__ float fast_rcp(float x) { return __builtin_amdgcn_rcpf(x); }
__device__ __forceinline__ float sigm(float x) { return fast_rcp(1.0f + __expf(-x)); }
__device__ __forceinline__ float tanh_e(float y) { return 1.0f - 2.0f * fast_rcp(1.0f + __expf(y)); }
__device__ __forceinline__ float tanh_raw(float x) { return tanh_e(2.0f * x); }

__global__ void precompute_kernel(const float* __restrict__ Ws, const float* __restrict__ bs,
                                  const float* __restrict__ Wd, const float* __restrict__ bd,
                                  const float* __restrict__ Wdec, const float* __restrict__ bdec,
                                  const float* __restrict__ W_ih, const float* __restrict__ b_ih,
                                  const float* __restrict__ Wa, const float* __restrict__ va,
                                  const float* __restrict__ Wp, const float* __restrict__ vp,
                                  float* __restrict__ ws)
{
    int tid = blockIdx.x * blockDim.x + threadIdx.x;
    if (tid < 768) {                              // Mgi
        int j = tid; const float* wr = &W_ih[j * NH];
        float m0 = 0.f, m1 = 0.f;
        for (int k = 0; k < NH; k++) { float w = wr[k]; m0 = fmaf(w, Wdec[2*k], m0); m1 = fmaf(w, Wdec[2*k+1], m1); }
        ws[2*j] = m0; ws[2*j+1] = m1;
    } else if (tid < 1536) {                      // cgi
        int j = tid - 768; const float* wr = &W_ih[j * NH];
        float c = b_ih[j];
        for (int k = 0; k < NH; k++) c = fmaf(wr[k], bdec[k], c);
        ws[1536 + j] = c;
    } else if (tid < 1792) {                      // cA (x2 scaled except va)
        int h = tid - 1536; const float* war = &Wa[h * NH3];
        float as0 = 0.f, as1 = 0.f, ad1 = 0.f;
        for (int k = 0; k < NH; k++) {
            float w = war[k];
            as0 = fmaf(w, Ws[2*k], as0); as1 = fmaf(w, Ws[2*k+1], as1);
            ad1 = fmaf(war[NH + k], Wd[2*k+1], ad1);
        }
        float4 v = make_float4(2.f*as0, 2.f*as1, 2.f*ad1, va[h]);
        ((float4*)(ws + 2304))[h] = v;
    } else if (tid < 2048) {                      // a0 (x2)
        int h = tid - 1792; const float* war = &Wa[h * NH3];
        float a = 0.f;
        for (int k = 0; k < NH; k++) {
            a = fmaf(war[k], bs[k], a);
            a = fmaf(war[NH + k], fmaf(20.0f, Wd[2*k], bd[k]), a);
        }
        ws[3328 + h] = 2.f * a;
    } else if (tid < 2304) {                      // cP (x2 scaled except vp)
        int h = tid - 2048; const float* wpr = &Wp[h * 2 * NH];
        float p0 = 0.f, p1 = 0.f;
        for (int k = 0; k < NH; k++) { float w = wpr[k]; p0 = fmaf(w, Ws[2*k], p0); p1 = fmaf(w, Ws[2*k+1], p1); }
        float4 v = make_float4(2.f*p0, 2.f*p1, vp[h], 0.f);
        ((float4*)(ws + 3584))[h] = v;
    } else if (tid < 2560) {                      // cP2: (2*PC0, 2*PC1, 2*pb)
        int h = tid - 2304;
        const float* wps = &Wp[h * 2 * NH];
        const float* wpc = wps + NH;
        float p0 = 0.f, p1 = 0.f, pb = 0.f;
        for (int k = 0; k < NH; k++) {
            p0 = fmaf(wpc[k], Ws[2*k], p0);
            p1 = fmaf(wpc[k], Ws[2*k+1], p1);
            pb = fmaf(wps[k] + wpc[k], bs[k], pb);
        }
        float4 v = make_float4(2.f*p0, 2.f*p1, 2.f*pb, 0.f);
        ((float4*)(ws + 70912))[h] = v;
    } else if (tid < 2560 + 65536) {              // WaH pack (x2)
        int m = tid - 2560; int i = m >> 8, j = m & 255;
        ws[5376 + m] = 2.f * Wa[i * NH3 + 2 * NH + j];
    }
}

__global__ void __launch_bounds__(512, 1)
drl_main(const float* __restrict__ gstatic, const float* __restrict__ gdyn,
         const float* __restrict__ glast, const float* __restrict__ gWhh,
         const float* __restrict__ gbhh, const float* __restrict__ wsb,
         float* __restrict__ out)
{
    __shared__ float s0[2][NN], s1[2][NN], d1[2][NN];
    __shared__ float hs[2][NH];
    __shared__ float ghs[2][NH3];
    __shared__ float qp[2][NH];
    __shared__ float4 cA[NH];
    __shared__ float4 cP[NH];
    __shared__ float4 cP2[NH];
    __shared__ float2 Mgi[NH3];
    __shared__ float cgi[NH3], bhh[NH3];
    __shared__ float a0v[NH];
    __shared__ float spart[2][NN * 9];     // attention partials, +1 pad stride
    __shared__ float Sw[2][2];
    __shared__ int idxs[2];

    const int t = threadIdx.x;
    const int g = t >> 8;          // batch elem within block
    const int r = t & 255;
    const int b0 = blockIdx.x * 2;

    // ---- stage inputs + coefficients into LDS
    for (int i = t; i < 2 * NN; i += 512) {
        int gg = i >> 7, n = i & 127, b = b0 + gg;
        s0[gg][n] = gstatic[b * (NF * NN) + n];
        s1[gg][n] = gstatic[b * (NF * NN) + NN + n];
        d1[gg][n] = gdyn[b * (NF * NN) + NN + n];
    }
    for (int i = t; i < 2 * NH; i += 512) {
        int gg = i >> 8, j = i & 255;
        hs[gg][j] = glast[(b0 + gg) * NH + j];
    }
    for (int i = t; i < 1536; i += 512) ((float*)Mgi)[i] = wsb[i];
    for (int i = t; i < 768;  i += 512) cgi[i] = wsb[1536 + i];
    for (int i = t; i < 1024; i += 512) ((float*)cA)[i] = wsb[2304 + i];
    if (t < 256) a0v[t] = wsb[3328 + t];
    for (int i = t; i < 1024; i += 512) ((float*)cP)[i] = wsb[3584 + i];
    for (int i = t; i < 1024; i += 512) ((float*)cP2)[i] = wsb[70912 + i];
    for (int i = t; i < 768;  i += 512) bhh[i] = gbhh[i];
    if (t == 0) { idxs[0] = 0; idxs[1] = 0; }
    __syncthreads();

    const float* WaH = wsb + 5376;
    const int jb = t >> 2, kq = t & 3;     // GEMV tiling (fused phases)
    const int jb2 = t >> 1, kh = t & 1;    // qp GEMV tiling

    // attention tiling: thread owns n-set {n0..n0+3}, h-set {hg + 8*hl}
    const int ng = r >> 3, hg = r & 7;
    const int n0 = ng * 4;
    float sv0[4], sv1[4], dv[4];
    #pragma unroll
    for (int j = 0; j < 4; j++) {
        sv0[j] = s0[g][n0 + j]; sv1[j] = s1[g][n0 + j]; dv[j] = d1[g][n0 + j];
    }
    float cwsum = 0.f, vpsum = 0.f;
    #pragma unroll 8
    for (int hl = 0; hl < 32; hl++) {
        cwsum += cA[hg + 8 * hl].w;
        vpsum += cP[hg + 8 * hl].z;
    }

    // ---- initial gh = W_hh*last_hh + b_hh (full 768 rows)
    {
        float acc[12];
        #pragma unroll
        for (int i = 0; i < 12; i++) acc[i] = 0.f;
        const float* wb = gWhh + jb * NH + 4 * kq;
        #pragma unroll 2
        for (int c = 0; c < 16; c++) {
            float4 h0 = *(const float4*)&hs[0][16 * c + 4 * kq];
            float4 h1 = *(const float4*)&hs[1][16 * c + 4 * kq];
            #pragma unroll
            for (int p = 0; p < 6; p++) {
                float4 w = *(const float4*)(wb + p * 128 * NH + 16 * c);
                acc[2*p]   = fmaf(w.x,h0.x,fmaf(w.y,h0.y,fmaf(w.z,h0.z,fmaf(w.w,h0.w,acc[2*p]))));
                acc[2*p+1] = fmaf(w.x,h1.x,fmaf(w.y,h1.y,fmaf(w.z,h1.z,fmaf(w.w,h1.w,acc[2*p+1]))));
            }
        }
        #pragma unroll
        for (int p = 0; p < 6; p++) {
            float u0 = acc[2*p], u1 = acc[2*p+1];
            u0 += __shfl_xor(u0, 1); u0 += __shfl_xor(u0, 2);
            u1 += __shfl_xor(u1, 1); u1 += __shfl_xor(u1, 2);
            if (kq == 0) { int j = jb + 128 * p; ghs[0][j] = u0 + bhh[j]; ghs[1][j] = u1 + bhh[j]; }
        }
    }
    __syncthreads();

    for (int step = 0; step < NN; step++) {
        // ---- P2: GRU elementwise
        {
            int id = idxs[g];
            float svA = s0[g][id], svB = s1[g][id];
            float2 m0 = Mgi[r], m1 = Mgi[NH + r], m2 = Mgi[2 * NH + r];
            float ir  = fmaf(m0.x, svA, fmaf(m0.y, svB, cgi[r]));
            float iz  = fmaf(m1.x, svA, fmaf(m1.y, svB, cgi[NH + r]));
            float inn = fmaf(m2.x, svA, fmaf(m2.y, svB, cgi[2 * NH + r]));
            float rr = sigm(ir + ghs[g][r]);
            float zz = sigm(iz + ghs[g][NH + r]);
            float nv = tanh_raw(fmaf(rr, ghs[g][2 * NH + r], inn));
            float ho = hs[g][r];
            hs[g][r] = fmaf(zz, ho - nv, nv);
        }
        __syncthreads();
        // ---- B: qp = 2*Wa_h*h + a0  (256 rows x 2 batch, 512 thr)
        {
            float u0 = 0.f, u1 = 0.f;
            const float* wq = WaH + jb2 * NH + 4 * kh;
            #pragma unroll 4
            for (int ks = 0; ks < 32; ks++) {
                float4 w  = *(const float4*)(wq + ks * 8);
                float4 h0 = *(const float4*)&hs[0][ks * 8 + 4 * kh];
                float4 h1 = *(const float4*)&hs[1][ks * 8 + 4 * kh];
                u0 = fmaf(w.x,h0.x,fmaf(w.y,h0.y,fmaf(w.z,h0.z,fmaf(w.w,h0.w,u0))));
                u1 = fmaf(w.x,h1.x,fmaf(w.y,h1.y,fmaf(w.z,h1.z,fmaf(w.w,h1.w,u1))));
            }
            u0 += __shfl_xor(u0, 1);
            u1 += __shfl_xor(u1, 1);
            if (kh == 0) { qp[0][jb2] = u0 + a0v[jb2]; qp[1][jb2] = u1 + a0v[jb2]; }
        }
        __syncthreads();
        // ---- C: fused W_hh rows [0,384) GEMV  +  attention scan P4
        {
            float a6[6];
            #pragma unroll
            for (int i = 0; i < 6; i++) a6[i] = 0.f;
            float at4[4] = {cwsum, cwsum, cwsum, cwsum};
            const float* wb = gWhh + jb * NH + 4 * kq;
            float4 wreg[2][3];
            #pragma unroll
            for (int p = 0; p < 3; p++) wreg[0][p] = *(const float4*)(wb + p * 128 * NH);
            #pragma unroll
            for (int ks = 0; ks < 16; ks++) {
                if (ks < 15) {
                    #pragma unroll
                    for (int p = 0; p < 3; p++)
                        wreg[(ks+1)&1][p] = *(const float4*)(wb + p * 128 * NH + (ks+1) * 16);
                }
                // two attention h-iterations between load issue and use
                #pragma unroll
                for (int u = 0; u < 2; u++) {
                    int h = hg + 8 * (2 * ks + u);
                    float4 c4 = cA[h];
                    float qv = qp[g][h];
                    float m2 = -2.f * c4.w;
                    #pragma unroll
                    for (int j = 0; j < 4; j++) {
                        float x = fmaf(c4.x, sv0[j], fmaf(c4.y, sv1[j], fmaf(c4.z, dv[j], qv)));
                        float rr = fast_rcp(1.0f + __expf(x));
                        at4[j] = fmaf(m2, rr, at4[j]);
                    }
                }
                float4 h0 = *(const float4*)&hs[0][ks * 16 + 4 * kq];
                float4 h1 = *(const float4*)&hs[1][ks * 16 + 4 * kq];
                #pragma unroll
                for (int p = 0; p < 3; p++) {
                    float4 w = wreg[ks&1][p];
                    a6[2*p]   = fmaf(w.x,h0.x,fmaf(w.y,h0.y,fmaf(w.z,h0.z,fmaf(w.w,h0.w,a6[2*p]))));
                    a6[2*p+1] = fmaf(w.x,h1.x,fmaf(w.y,h1.y,fmaf(w.z,h1.z,fmaf(w.w,h1.w,a6[2*p+1]))));
                }
            }
            #pragma unroll
            for (int j = 0; j < 4; j++) spart[g][(n0 + j) * 9 + hg] = at4[j];
            #pragma unroll
            for (int p = 0; p < 3; p++) {
                float u0 = a6[2*p], u1 = a6[2*p+1];
                u0 += __shfl_xor(u0, 1); u0 += __shfl_xor(u0, 2);
                u1 += __shfl_xor(u1, 1); u1 += __shfl_xor(u1, 2);
                if (kq == 0) { int j = jb + 128 * p; ghs[0][j] = u0 + bhh[j]; ghs[1][j] = u1 + bhh[j]; }
            }
        }
        __syncthreads();
        // ---- P5: sum partials + softmax over n -> weighted sums S0w,S1w
        if (r < 64) {
            int l = r;
            float v0 = 0.f, v1 = 0.f;
            #pragma unroll
            for (int hq = 0; hq < 8; hq++) {
                v0 += spart[g][l * 9 + hq];
                v1 += spart[g][(l + 64) * 9 + hq];
            }
            float m = fmaxf(v0, v1);
            #pragma unroll
            for (int o = 32; o; o >>= 1) m = fmaxf(m, __shfl_xor(m, o));
            float e0 = __expf(v0 - m), e1 = __expf(v1 - m);
            float ss = e0 + e1;
            #pragma unroll
            for (int o = 32; o; o >>= 1) ss += __shfl_xor(ss, o);
            float rs = fast_rcp(ss);
            float w0 = e0 * rs, w1 = e1 * rs;
            float t0 = fmaf(w0, s0[g][l], w1 * s0[g][l + 64]);
            float t1 = fmaf(w0, s1[g][l], w1 * s1[g][l + 64]);
            #pragma unroll
            for (int o = 32; o; o >>= 1) { t0 += __shfl_xor(t0, o); t1 += __shfl_xor(t1, o); }
            if (l == 0) { Sw[g][0] = t0; Sw[g][1] = t1; }
        }
        __syncthreads();
        // ---- P7: fused W_hh rows [384,768) GEMV  +  pointer scan
        {
            float S0 = Sw[g][0], S1 = Sw[g][1];
            float a6[6];
            #pragma unroll
            for (int i = 0; i < 6; i++) a6[i] = 0.f;
            float at4[4] = {vpsum, vpsum, vpsum, vpsum};
            const float* wb = gWhh + (384 + jb) * NH + 4 * kq;
            float4 wreg[2][3];
            #pragma unroll
            for (int p = 0; p < 3; p++) wreg[0][p] = *(const float4*)(wb + p * 128 * NH);
            #pragma unroll
            for (int ks = 0; ks < 16; ks++) {
                if (ks < 15) {
                    #pragma unroll
                    for (int p = 0; p < 3; p++)
                        wreg[(ks+1)&1][p] = *(const float4*)(wb + p * 128 * NH + (ks+1) * 16);
                }
                #pragma unroll
                for (int u = 0; u < 2; u++) {
                    int h = hg + 8 * (2 * ks + u);
                    float4 c4 = cP[h];
                    float4 c2 = cP2[h];
                    float pc = fmaf(c2.x, S0, fmaf(c2.y, S1, c2.z));
                    float m2 = -2.f * c4.z;
                    #pragma unroll
                    for (int j = 0; j < 4; j++) {
                        float x = fmaf(c4.x, sv0[j], fmaf(c4.y, sv1[j], pc));
                        float rr = fast_rcp(1.0f + __expf(x));
                        at4[j] = fmaf(m2, rr, at4[j]);
                    }
                }
                float4 h0 = *(const float4*)&hs[0][ks * 16 + 4 * kq];
                float4 h1 = *(const float4*)&hs[1][ks * 16 + 4 * kq];
                #pragma unroll
                for (int p = 0; p < 3; p++) {
                    float4 w = wreg[ks&1][p];
                    a6[2*p]   = fmaf(w.x,h0.x,fmaf(w.y,h0.y,fmaf(w.z,h0.z,fmaf(w.w,h0.w,a6[2*p]))));
                    a6[2*p+1] = fmaf(w.x,h1.x,fmaf(w.y,h1.y,fmaf(w.z,h1.z,fmaf(w.w,h1.w,a6[2*p+1]))));
                }
            }
            #pragma unroll
            for (int j = 0; j < 4; j++) spart[g][(n0 + j) * 9 + hg] = at4[j];
            #pragma unroll
            for (int p = 0; p < 3; p++) {
                float u0 = a6[2*p], u1 = a6[2*p+1];
                u0 += __shfl_xor(u0, 1); u0 += __shfl_xor(u0, 2);
                u1 += __shfl_xor(u1, 1); u1 += __shfl_xor(u1, 2);
                if (kq == 0) { int j = 384 + jb + 128 * p; ghs[0][j] = u0 + bhh[j]; ghs[1][j] = u1 + bhh[j]; }
            }
        }
        __syncthreads();
        // ---- P8: sum partials + softmax + argmax (first-index tiebreak) + outputs
        if (r < 64) {
            int l = r;
            float v0 = 0.f, v1 = 0.f;
            #pragma unroll
            for (int hq = 0; hq < 8; hq++) {
                v0 += spart[g][l * 9 + hq];
                v1 += spart[g][(l + 64) * 9 + hq];
            }
            float bv = v0; int bi = l;
            if (v1 > v0) { bv = v1; bi = l + 64; }
            #pragma unroll
            for (int o = 32; o; o >>= 1) {
                float ov = __shfl_xor(bv, o); int oi = __shfl_xor(bi, o);
                if (ov > bv || (ov == bv && oi < bi)) { bv = ov; bi = oi; }
            }
            float e0 = __expf(v0 - bv), e1 = __expf(v1 - bv);
            float ss = e0 + e1;
            #pragma unroll
            for (int o = 32; o; o >>= 1) ss += __shfl_xor(ss, o);
            if (l == 0) {
                idxs[g] = bi;
                int b = b0 + g;
                out[b * NN + step] = (float)bi;
                out[NB * NN + b * NN + step] = -logf(ss);
            }
        }
        __syncthreads();
    }
}

extern "C" void kernel_launch(void* const* d_in, const int* in_sizes, int n_in,
                              void* d_out, int out_size, void* d_ws, size_t ws_size,
                              hipStream_t stream) {
    const float* gstatic = (const float*)d_in[0];
    const float* gdyn    = (const float*)d_in[1];
    const float* glast   = (const float*)d_in[2];
    const float* Ws      = (const float*)d_in[3];
    const float* bs      = (const float*)d_in[4];
    const float* Wd      = (const float*)d_in[5];
    const float* bd      = (const float*)d_in[6];
    const float* Wdec    = (const float*)d_in[7];
    const float* bdec    = (const float*)d_in[8];
    const float* W_ih    = (const float*)d_in[9];
    const float* W_hh    = (const float*)d_in[10];
    const float* b_ih    = (const float*)d_in[11];
    const float* b_hh    = (const float*)d_in[12];
    const float* Wa      = (const float*)d_in[13];
    const float* va      = (const float*)d_in[14];
    const float* Wp      = (const float*)d_in[15];
    const float* vp      = (const float*)d_in[16];
    float* outp = (float*)d_out;
    float* wsb  = (float*)d_ws;

    // 2560 coefficient dots + 65536 WaH pack = 68096 tasks
    precompute_kernel<<<267, 256, 0, stream>>>(Ws, bs, Wd, bd, Wdec, bdec,
                                               W_ih, b_ih, Wa, va, Wp, vp, wsb);
    drl_main<<<256, 512, 0, stream>>>(gstatic, gdyn, glast, W_hh, b_hh, wsb, outp);
}

// Round 4
// 2514.452 us; speedup vs baseline: 2.9422x; 2.9422x over previous
//
#include <hip/hip_runtime.h>
#include <math.h>

// DRL4TSP decode: B=512, F=2, N=128, H=256, 128 steps.
// One workgroup (512 thr) owns 2 batch elems; all 128 steps in-kernel.
// R4: R2's manual double-buffer wreg[2][3] was dynamically indexed ((ks+1)&1)
// inside a not-fully-unrolled loop -> lowered to SCRATCH (427MB HBM writeback,
// L2 thrash, weights lost residency -> FETCH 10.5GB). Fix: no local arrays
// with dynamic indices; plain w0/w1/w2 scalars loaded at top of iteration,
// attention math between issue and use (compiler waitcnt gives the overlap).

#define NB 512
#define NF 2
#define NN 128
#define NH 256
#define NH3 768

// ws layout (floats):
//   0     : Mgi[768] float2   (W_ih·Wdec, 2 cols interleaved)
//   1536  : cgi[768]          (W_ih·bdec + b_ih)
//   2304  : cA[256] float4    (2*A_s0, 2*A_s1, 2*A_d1, va)
//   3328  : a0[256]           (2*(Wa_s·bs + Wa_d·(20*Wd0+bd)))
//   3584  : cP[256] float4    (2*P_s0, 2*P_s1, vp, 0)
//   5376  : WaH[256*256]      (2*Wa[:,2H:3H] row-major)
//   70912 : cP2[256] float4   (2*PC0, 2*PC1, 2*pb, 0)
// x2 pre-scaling folds tanh(x)=1-2/(1+exp(2x)) exactly.

__device__ __forceinline__ float fast_rcp(float x) { return __builtin_amdgcn_rcpf(x); }
__device__ __forceinline__ float sigm(float x) { return fast_rcp(1.0f + __expf(-x)); }
__device__ __forceinline__ float tanh_e(float y) { return 1.0f - 2.0f * fast_rcp(1.0f + __expf(y)); }
__device__ __forceinline__ float tanh_raw(float x) { return tanh_e(2.0f * x); }

__global__ void precompute_kernel(const float* __restrict__ Ws, const float* __restrict__ bs,
                                  const float* __restrict__ Wd, const float* __restrict__ bd,
                                  const float* __restrict__ Wdec, const float* __restrict__ bdec,
                                  const float* __restrict__ W_ih, const float* __restrict__ b_ih,
                                  const float* __restrict__ Wa, const float* __restrict__ va,
                                  const float* __restrict__ Wp, const float* __restrict__ vp,
                                  float* __restrict__ ws)
{
    int tid = blockIdx.x * blockDim.x + threadIdx.x;
    if (tid < 768) {                              // Mgi
        int j = tid; const float* wr = &W_ih[j * NH];
        float m0 = 0.f, m1 = 0.f;
        for (int k = 0; k < NH; k++) { float w = wr[k]; m0 = fmaf(w, Wdec[2*k], m0); m1 = fmaf(w, Wdec[2*k+1], m1); }
        ws[2*j] = m0; ws[2*j+1] = m1;
    } else if (tid < 1536) {                      // cgi
        int j = tid - 768; const float* wr = &W_ih[j * NH];
        float c = b_ih[j];
        for (int k = 0; k < NH; k++) c = fmaf(wr[k], bdec[k], c);
        ws[1536 + j] = c;
    } else if (tid < 1792) {                      // cA (x2 scaled except va)
        int h = tid - 1536; const float* war = &Wa[h * NH3];
        float as0 = 0.f, as1 = 0.f, ad1 = 0.f;
        for (int k = 0; k < NH; k++) {
            float w = war[k];
            as0 = fmaf(w, Ws[2*k], as0); as1 = fmaf(w, Ws[2*k+1], as1);
            ad1 = fmaf(war[NH + k], Wd[2*k+1], ad1);
        }
        float4 v = make_float4(2.f*as0, 2.f*as1, 2.f*ad1, va[h]);
        ((float4*)(ws + 2304))[h] = v;
    } else if (tid < 2048) {                      // a0 (x2)
        int h = tid - 1792; const float* war = &Wa[h * NH3];
        float a = 0.f;
        for (int k = 0; k < NH; k++) {
            a = fmaf(war[k], bs[k], a);
            a = fmaf(war[NH + k], fmaf(20.0f, Wd[2*k], bd[k]), a);
        }
        ws[3328 + h] = 2.f * a;
    } else if (tid < 2304) {                      // cP (x2 scaled except vp)
        int h = tid - 2048; const float* wpr = &Wp[h * 2 * NH];
        float p0 = 0.f, p1 = 0.f;
        for (int k = 0; k < NH; k++) { float w = wpr[k]; p0 = fmaf(w, Ws[2*k], p0); p1 = fmaf(w, Ws[2*k+1], p1); }
        float4 v = make_float4(2.f*p0, 2.f*p1, vp[h], 0.f);
        ((float4*)(ws + 3584))[h] = v;
    } else if (tid < 2560) {                      // cP2: (2*PC0, 2*PC1, 2*pb)
        int h = tid - 2304;
        const float* wps = &Wp[h * 2 * NH];
        const float* wpc = wps + NH;
        float p0 = 0.f, p1 = 0.f, pb = 0.f;
        for (int k = 0; k < NH; k++) {
            p0 = fmaf(wpc[k], Ws[2*k], p0);
            p1 = fmaf(wpc[k], Ws[2*k+1], p1);
            pb = fmaf(wps[k] + wpc[k], bs[k], pb);
        }
        float4 v = make_float4(2.f*p0, 2.f*p1, 2.f*pb, 0.f);
        ((float4*)(ws + 70912))[h] = v;
    } else if (tid < 2560 + 65536) {              // WaH pack (x2)
        int m = tid - 2560; int i = m >> 8, j = m & 255;
        ws[5376 + m] = 2.f * Wa[i * NH3 + 2 * NH + j];
    }
}

__global__ void __launch_bounds__(512, 1)
drl_main(const float* __restrict__ gstatic, const float* __restrict__ gdyn,
         const float* __restrict__ glast, const float* __restrict__ gWhh,
         const float* __restrict__ gbhh, const float* __restrict__ wsb,
         float* __restrict__ out)
{
    __shared__ float s0[2][NN], s1[2][NN], d1[2][NN];
    __shared__ float hs[2][NH];
    __shared__ float ghs[2][NH3];
    __shared__ float qp[2][NH];
    __shared__ float4 cA[NH];
    __shared__ float4 cP[NH];
    __shared__ float4 cP2[NH];
    __shared__ float2 Mgi[NH3];
    __shared__ float cgi[NH3], bhh[NH3];
    __shared__ float a0v[NH];
    __shared__ float spart[2][NN * 9];     // attention partials, +1 pad stride
    __shared__ float Sw[2][2];
    __shared__ int idxs[2];

    const int t = threadIdx.x;
    const int g = t >> 8;          // batch elem within block
    const int r = t & 255;
    const int b0 = blockIdx.x * 2;

    // ---- stage inputs + coefficients into LDS
    for (int i = t; i < 2 * NN; i += 512) {
        int gg = i >> 7, n = i & 127, b = b0 + gg;
        s0[gg][n] = gstatic[b * (NF * NN) + n];
        s1[gg][n] = gstatic[b * (NF * NN) + NN + n];
        d1[gg][n] = gdyn[b * (NF * NN) + NN + n];
    }
    for (int i = t; i < 2 * NH; i += 512) {
        int gg = i >> 8, j = i & 255;
        hs[gg][j] = glast[(b0 + gg) * NH + j];
    }
    for (int i = t; i < 1536; i += 512) ((float*)Mgi)[i] = wsb[i];
    for (int i = t; i < 768;  i += 512) cgi[i] = wsb[1536 + i];
    for (int i = t; i < 1024; i += 512) ((float*)cA)[i] = wsb[2304 + i];
    if (t < 256) a0v[t] = wsb[3328 + t];
    for (int i = t; i < 1024; i += 512) ((float*)cP)[i] = wsb[3584 + i];
    for (int i = t; i < 1024; i += 512) ((float*)cP2)[i] = wsb[70912 + i];
    for (int i = t; i < 768;  i += 512) bhh[i] = gbhh[i];
    if (t == 0) { idxs[0] = 0; idxs[1] = 0; }
    __syncthreads();

    const float* WaH = wsb + 5376;
    const int jb = t >> 2, kq = t & 3;     // GEMV tiling (fused phases)
    const int jb2 = t >> 1, kh = t & 1;    // qp GEMV tiling

    // attention tiling: thread owns n-set {n0..n0+3}, h-set {hg + 8*hl}
    const int ng = r >> 3, hg = r & 7;
    const int n0 = ng * 4;
    float sv0[4], sv1[4], dv[4];
    #pragma unroll
    for (int j = 0; j < 4; j++) {
        sv0[j] = s0[g][n0 + j]; sv1[j] = s1[g][n0 + j]; dv[j] = d1[g][n0 + j];
    }
    float cwsum = 0.f, vpsum = 0.f;
    #pragma unroll 8
    for (int hl = 0; hl < 32; hl++) {
        cwsum += cA[hg + 8 * hl].w;
        vpsum += cP[hg + 8 * hl].z;
    }

    // ---- initial gh = W_hh*last_hh + b_hh (full 768 rows)
    {
        float acc[12];
        #pragma unroll
        for (int i = 0; i < 12; i++) acc[i] = 0.f;
        const float* wb = gWhh + jb * NH + 4 * kq;
        #pragma unroll 2
        for (int c = 0; c < 16; c++) {
            float4 h0 = *(const float4*)&hs[0][16 * c + 4 * kq];
            float4 h1 = *(const float4*)&hs[1][16 * c + 4 * kq];
            #pragma unroll
            for (int p = 0; p < 6; p++) {
                float4 w = *(const float4*)(wb + p * 128 * NH + 16 * c);
                acc[2*p]   = fmaf(w.x,h0.x,fmaf(w.y,h0.y,fmaf(w.z,h0.z,fmaf(w.w,h0.w,acc[2*p]))));
                acc[2*p+1] = fmaf(w.x,h1.x,fmaf(w.y,h1.y,fmaf(w.z,h1.z,fmaf(w.w,h1.w,acc[2*p+1]))));
            }
        }
        #pragma unroll
        for (int p = 0; p < 6; p++) {
            float u0 = acc[2*p], u1 = acc[2*p+1];
            u0 += __shfl_xor(u0, 1); u0 += __shfl_xor(u0, 2);
            u1 += __shfl_xor(u1, 1); u1 += __shfl_xor(u1, 2);
            if (kq == 0) { int j = jb + 128 * p; ghs[0][j] = u0 + bhh[j]; ghs[1][j] = u1 + bhh[j]; }
        }
    }
    __syncthreads();

    for (int step = 0; step < NN; step++) {
        // ---- P2: GRU elementwise
        {
            int id = idxs[g];
            float svA = s0[g][id], svB = s1[g][id];
            float2 m0 = Mgi[r], m1 = Mgi[NH + r], m2 = Mgi[2 * NH + r];
            float ir  = fmaf(m0.x, svA, fmaf(m0.y, svB, cgi[r]));
            float iz  = fmaf(m1.x, svA, fmaf(m1.y, svB, cgi[NH + r]));
            float inn = fmaf(m2.x, svA, fmaf(m2.y, svB, cgi[2 * NH + r]));
            float rr = sigm(ir + ghs[g][r]);
            float zz = sigm(iz + ghs[g][NH + r]);
            float nv = tanh_raw(fmaf(rr, ghs[g][2 * NH + r], inn));
            float ho = hs[g][r];
            hs[g][r] = fmaf(zz, ho - nv, nv);
        }
        __syncthreads();
        // ---- B: qp = 2*Wa_h*h + a0  (256 rows x 2 batch, 512 thr)
        {
            float u0 = 0.f, u1 = 0.f;
            const float* wq = WaH + jb2 * NH + 4 * kh;
            #pragma unroll 4
            for (int ks = 0; ks < 32; ks++) {
                float4 w  = *(const float4*)(wq + ks * 8);
                float4 h0 = *(const float4*)&hs[0][ks * 8 + 4 * kh];
                float4 h1 = *(const float4*)&hs[1][ks * 8 + 4 * kh];
                u0 = fmaf(w.x,h0.x,fmaf(w.y,h0.y,fmaf(w.z,h0.z,fmaf(w.w,h0.w,u0))));
                u1 = fmaf(w.x,h1.x,fmaf(w.y,h1.y,fmaf(w.z,h1.z,fmaf(w.w,h1.w,u1))));
            }
            u0 += __shfl_xor(u0, 1);
            u1 += __shfl_xor(u1, 1);
            if (kh == 0) { qp[0][jb2] = u0 + a0v[jb2]; qp[1][jb2] = u1 + a0v[jb2]; }
        }
        __syncthreads();
        // ---- C: fused W_hh rows [0,384) GEMV  +  attention scan P4
        // (no local arrays with dynamic indices -> no scratch)
        {
            float a0a = 0.f, a1a = 0.f, a2a = 0.f, a3a = 0.f, a4a = 0.f, a5a = 0.f;
            float at0 = cwsum, at1 = cwsum, at2 = cwsum, at3 = cwsum;
            const float* wb = gWhh + jb * NH + 4 * kq;
            #pragma unroll 1
            for (int ks = 0; ks < 16; ks++) {
                // issue the three L2-stream loads first
                float4 w0 = *(const float4*)(wb + 0 * 128 * NH + ks * 16);
                float4 w1 = *(const float4*)(wb + 1 * 128 * NH + ks * 16);
                float4 w2 = *(const float4*)(wb + 2 * 128 * NH + ks * 16);
                // attention math for 2 h-values sits between issue and use
                #pragma unroll
                for (int u = 0; u < 2; u++) {
                    int h = hg + 8 * (2 * ks + u);
                    float4 c4 = cA[h];
                    float qv = qp[g][h];
                    float m2 = -2.f * c4.w;
                    float x0 = fmaf(c4.x, sv0[0], fmaf(c4.y, sv1[0], fmaf(c4.z, dv[0], qv)));
                    float x1 = fmaf(c4.x, sv0[1], fmaf(c4.y, sv1[1], fmaf(c4.z, dv[1], qv)));
                    float x2 = fmaf(c4.x, sv0[2], fmaf(c4.y, sv1[2], fmaf(c4.z, dv[2], qv)));
                    float x3 = fmaf(c4.x, sv0[3], fmaf(c4.y, sv1[3], fmaf(c4.z, dv[3], qv)));
                    at0 = fmaf(m2, fast_rcp(1.0f + __expf(x0)), at0);
                    at1 = fmaf(m2, fast_rcp(1.0f + __expf(x1)), at1);
                    at2 = fmaf(m2, fast_rcp(1.0f + __expf(x2)), at2);
                    at3 = fmaf(m2, fast_rcp(1.0f + __expf(x3)), at3);
                }
                float4 h0 = *(const float4*)&hs[0][ks * 16 + 4 * kq];
                float4 h1 = *(const float4*)&hs[1][ks * 16 + 4 * kq];
                a0a = fmaf(w0.x,h0.x,fmaf(w0.y,h0.y,fmaf(w0.z,h0.z,fmaf(w0.w,h0.w,a0a))));
                a1a = fmaf(w0.x,h1.x,fmaf(w0.y,h1.y,fmaf(w0.z,h1.z,fmaf(w0.w,h1.w,a1a))));
                a2a = fmaf(w1.x,h0.x,fmaf(w1.y,h0.y,fmaf(w1.z,h0.z,fmaf(w1.w,h0.w,a2a))));
                a3a = fmaf(w1.x,h1.x,fmaf(w1.y,h1.y,fmaf(w1.z,h1.z,fmaf(w1.w,h1.w,a3a))));
                a4a = fmaf(w2.x,h0.x,fmaf(w2.y,h0.y,fmaf(w2.z,h0.z,fmaf(w2.w,h0.w,a4a))));
                a5a = fmaf(w2.x,h1.x,fmaf(w2.y,h1.y,fmaf(w2.z,h1.z,fmaf(w2.w,h1.w,a5a))));
            }
            spart[g][(n0 + 0) * 9 + hg] = at0;
            spart[g][(n0 + 1) * 9 + hg] = at1;
            spart[g][(n0 + 2) * 9 + hg] = at2;
            spart[g][(n0 + 3) * 9 + hg] = at3;
            a0a += __shfl_xor(a0a, 1); a0a += __shfl_xor(a0a, 2);
            a1a += __shfl_xor(a1a, 1); a1a += __shfl_xor(a1a, 2);
            a2a += __shfl_xor(a2a, 1); a2a += __shfl_xor(a2a, 2);
            a3a += __shfl_xor(a3a, 1); a3a += __shfl_xor(a3a, 2);
            a4a += __shfl_xor(a4a, 1); a4a += __shfl_xor(a4a, 2);
            a5a += __shfl_xor(a5a, 1); a5a += __shfl_xor(a5a, 2);
            if (kq == 0) {
                ghs[0][jb]       = a0a + bhh[jb];
                ghs[1][jb]       = a1a + bhh[jb];
                ghs[0][jb + 128] = a2a + bhh[jb + 128];
                ghs[1][jb + 128] = a3a + bhh[jb + 128];
                ghs[0][jb + 256] = a4a + bhh[jb + 256];
                ghs[1][jb + 256] = a5a + bhh[jb + 256];
            }
        }
        __syncthreads();
        // ---- P5: sum partials + softmax over n -> weighted sums S0w,S1w
        if (r < 64) {
            int l = r;
            float v0 = 0.f, v1 = 0.f;
            #pragma unroll
            for (int hq = 0; hq < 8; hq++) {
                v0 += spart[g][l * 9 + hq];
                v1 += spart[g][(l + 64) * 9 + hq];
            }
            float m = fmaxf(v0, v1);
            #pragma unroll
            for (int o = 32; o; o >>= 1) m = fmaxf(m, __shfl_xor(m, o));
            float e0 = __expf(v0 - m), e1 = __expf(v1 - m);
            float ss = e0 + e1;
            #pragma unroll
            for (int o = 32; o; o >>= 1) ss += __shfl_xor(ss, o);
            float rs = fast_rcp(ss);
            float w0 = e0 * rs, w1 = e1 * rs;
            float t0 = fmaf(w0, s0[g][l], w1 * s0[g][l + 64]);
            float t1 = fmaf(w0, s1[g][l], w1 * s1[g][l + 64]);
            #pragma unroll
            for (int o = 32; o; o >>= 1) { t0 += __shfl_xor(t0, o); t1 += __shfl_xor(t1, o); }
            if (l == 0) { Sw[g][0] = t0; Sw[g][1] = t1; }
        }
        __syncthreads();
        // ---- P7: fused W_hh rows [384,768) GEMV  +  pointer scan
        {
            float S0 = Sw[g][0], S1 = Sw[g][1];
            float a0a = 0.f, a1a = 0.f, a2a = 0.f, a3a = 0.f, a4a = 0.f, a5a = 0.f;
            float at0 = vpsum, at1 = vpsum, at2 = vpsum, at3 = vpsum;
            const float* wb = gWhh + (384 + jb) * NH + 4 * kq;
            #pragma unroll 1
            for (int ks = 0; ks < 16; ks++) {
                float4 w0 = *(const float4*)(wb + 0 * 128 * NH + ks * 16);
                float4 w1 = *(const float4*)(wb + 1 * 128 * NH + ks * 16);
                float4 w2 = *(const float4*)(wb + 2 * 128 * NH + ks * 16);
                #pragma unroll
                for (int u = 0; u < 2; u++) {
                    int h = hg + 8 * (2 * ks + u);
                    float4 c4 = cP[h];
                    float4 c2 = cP2[h];
                    float pc = fmaf(c2.x, S0, fmaf(c2.y, S1, c2.z));
                    float m2 = -2.f * c4.z;
                    float x0 = fmaf(c4.x, sv0[0], fmaf(c4.y, sv1[0], pc));
                    float x1 = fmaf(c4.x, sv0[1], fmaf(c4.y, sv1[1], pc));
                    float x2 = fmaf(c4.x, sv0[2], fmaf(c4.y, sv1[2], pc));
                    float x3 = fmaf(c4.x, sv0[3], fmaf(c4.y, sv1[3], pc));
                    at0 = fmaf(m2, fast_rcp(1.0f + __expf(x0)), at0);
                    at1 = fmaf(m2, fast_rcp(1.0f + __expf(x1)), at1);
                    at2 = fmaf(m2, fast_rcp(1.0f + __expf(x2)), at2);
                    at3 = fmaf(m2, fast_rcp(1.0f + __expf(x3)), at3);
                }
                float4 h0 = *(const float4*)&hs[0][ks * 16 + 4 * kq];
                float4 h1 = *(const float4*)&hs[1][ks * 16 + 4 * kq];
                a0a = fmaf(w0.x,h0.x,fmaf(w0.y,h0.y,fmaf(w0.z,h0.z,fmaf(w0.w,h0.w,a0a))));
                a1a = fmaf(w0.x,h1.x,fmaf(w0.y,h1.y,fmaf(w0.z,h1.z,fmaf(w0.w,h1.w,a1a))));
                a2a = fmaf(w1.x,h0.x,fmaf(w1.y,h0.y,fmaf(w1.z,h0.z,fmaf(w1.w,h0.w,a2a))));
                a3a = fmaf(w1.x,h1.x,fmaf(w1.y,h1.y,fmaf(w1.z,h1.z,fmaf(w1.w,h1.w,a3a))));
                a4a = fmaf(w2.x,h0.x,fmaf(w2.y,h0.y,fmaf(w2.z,h0.z,fmaf(w2.w,h0.w,a4a))));
                a5a = fmaf(w2.x,h1.x,fmaf(w2.y,h1.y,fmaf(w2.z,h1.z,fmaf(w2.w,h1.w,a5a))));
            }
            spart[g][(n0 + 0) * 9 + hg] = at0;
            spart[g][(n0 + 1) * 9 + hg] = at1;
            spart[g][(n0 + 2) * 9 + hg] = at2;
            spart[g][(n0 + 3) * 9 + hg] = at3;
            a0a += __shfl_xor(a0a, 1); a0a += __shfl_xor(a0a, 2);
            a1a += __shfl_xor(a1a, 1); a1a += __shfl_xor(a1a, 2);
            a2a += __shfl_xor(a2a, 1); a2a += __shfl_xor(a2a, 2);
            a3a += __shfl_xor(a3a, 1); a3a += __shfl_xor(a3a, 2);
            a4a += __shfl_xor(a4a, 1); a4a += __shfl_xor(a4a, 2);
            a5a += __shfl_xor(a5a, 1); a5a += __shfl_xor(a5a, 2);
            if (kq == 0) {
                ghs[0][384 + jb]       = a0a + bhh[384 + jb];
                ghs[1][384 + jb]       = a1a + bhh[384 + jb];
                ghs[0][512 + jb]       = a2a + bhh[512 + jb];
                ghs[1][512 + jb]       = a3a + bhh[512 + jb];
                ghs[0][640 + jb]       = a4a + bhh[640 + jb];
                ghs[1][640 + jb]       = a5a + bhh[640 + jb];
            }
        }
        __syncthreads();
        // ---- P8: sum partials + softmax + argmax (first-index tiebreak) + outputs
        if (r < 64) {
            int l = r;
            float v0 = 0.f, v1 = 0.f;
            #pragma unroll
            for (int hq = 0; hq < 8; hq++) {
                v0 += spart[g][l * 9 + hq];
                v1 += spart[g][(l + 64) * 9 + hq];
            }
            float bv = v0; int bi = l;
            if (v1 > v0) { bv = v1; bi = l + 64; }
            #pragma unroll
            for (int o = 32; o; o >>= 1) {
                float ov = __shfl_xor(bv, o); int oi = __shfl_xor(bi, o);
                if (ov > bv || (ov == bv && oi < bi)) { bv = ov; bi = oi; }
            }
            float e0 = __expf(v0 - bv), e1 = __expf(v1 - bv);
            float ss = e0 + e1;
            #pragma unroll
            for (int o = 32; o; o >>= 1) ss += __shfl_xor(ss, o);
            if (l == 0) {
                idxs[g] = bi;
                int b = b0 + g;
                out[b * NN + step] = (float)bi;
                out[NB * NN + b * NN + step] = -logf(ss);
            }
        }
        __syncthreads();
    }
}

extern "C" void kernel_launch(void* const* d_in, const int* in_sizes, int n_in,
                              void* d_out, int out_size, void* d_ws, size_t ws_size,
                              hipStream_t stream) {
    const float* gstatic = (const float*)d_in[0];
    const float* gdyn    = (const float*)d_in[1];
    const float* glast   = (const float*)d_in[2];
    const float* Ws      = (const float*)d_in[3];
    const float* bs      = (const float*)d_in[4];
    const float* Wd      = (const float*)d_in[5];
    const float* bd      = (const float*)d_in[6];
    const float* Wdec    = (const float*)d_in[7];
    const float* bdec    = (const float*)d_in[8];
    const float* W_ih    = (const float*)d_in[9];
    const float* W_hh    = (const float*)d_in[10];
    const float* b_ih    = (const float*)d_in[11];
    const float* b_hh    = (const float*)d_in[12];
    const float* Wa      = (const float*)d_in[13];
    const float* va      = (const float*)d_in[14];
    const float* Wp      = (const float*)d_in[15];
    const float* vp      = (const float*)d_in[16];
    float* outp = (float*)d_out;
    float* wsb  = (float*)d_ws;

    // 2560 coefficient dots + 65536 WaH pack = 68096 tasks
    precompute_kernel<<<267, 256, 0, stream>>>(Ws, bs, Wd, bd, Wdec, bdec,
                                               W_ih, b_ih, Wa, va, Wp, vp, wsb);
    drl_main<<<256, 512, 0, stream>>>(gstatic, gdyn, glast, W_hh, b_hh, wsb, outp);
}

// Round 5
// 2266.515 us; speedup vs baseline: 3.2640x; 1.1094x over previous
//
#include <hip/hip_runtime.h>
#include <math.h>

// DRL4TSP decode: B=512, F=2, N=128, H=256, 128 steps.
// R5: 1024-thread blocks (G=2 batch elems, grid=256) -> 4 waves/SIMD instead
// of 2, same per-CU L2 weight traffic; hides trans-pipe + L2 latency (R4 was
// stall-bound: real VALU busy ~34% after correcting the gfx94x-formula
// VALUBusy by 2x for SIMD-32). Also folds 2*log2(e) into all tanh-input
// coefficients and uses v_exp_f32 (exp2) directly, dropping the v_mul that
// __expf hides. No local arrays with dynamic indices (R3 scratch lesson).

#define NB 512
#define NF 2
#define NN 128
#define NH 256
#define NH3 768
#define SC 2.8853900817779268f   // 2*log2(e): folds tanh doubling + exp->exp2

// ws layout (floats):
//   0     : Mgi[768] float2   (W_ih·Wdec, 2 cols interleaved)   [unscaled]
//   1536  : cgi[768]          (W_ih·bdec + b_ih)                [unscaled]
//   2304  : cA[256] float4    (SC*A_s0, SC*A_s1, SC*A_d1, va)
//   3328  : a0[256]           (SC*(Wa_s·bs + Wa_d·(20*Wd0+bd)))
//   3584  : cP[256] float4    (SC*P_s0, SC*P_s1, vp, 0)
//   5376  : WaH[256*256]      (SC*Wa[:,2H:3H] row-major)
//   70912 : cP2[256] float4   (SC*PC0, SC*PC1, SC*pb, 0)
// tanh(x) = 1 - 2/(1+exp2(SC*x)); accumulate via fma(-2*v, rcp(1+exp2(y)), sum_v)

__device__ __forceinline__ float fast_rcp(float x) { return __builtin_amdgcn_rcpf(x); }
__device__ __forceinline__ float fast_exp2(float x) { return __builtin_amdgcn_exp2f(x); }
__device__ __forceinline__ float sigm(float x) { return fast_rcp(1.0f + __expf(-x)); }
__device__ __forceinline__ float tanh_raw(float x) { return 1.0f - 2.0f * fast_rcp(1.0f + fast_exp2(SC * x)); }

__global__ void precompute_kernel(const float* __restrict__ Ws, const float* __restrict__ bs,
                                  const float* __restrict__ Wd, const float* __restrict__ bd,
                                  const float* __restrict__ Wdec, const float* __restrict__ bdec,
                                  const float* __restrict__ W_ih, const float* __restrict__ b_ih,
                                  const float* __restrict__ Wa, const float* __restrict__ va,
                                  const float* __restrict__ Wp, const float* __restrict__ vp,
                                  float* __restrict__ ws)
{
    int tid = blockIdx.x * blockDim.x + threadIdx.x;
    if (tid < 768) {                              // Mgi
        int j = tid; const float* wr = &W_ih[j * NH];
        float m0 = 0.f, m1 = 0.f;
        for (int k = 0; k < NH; k++) { float w = wr[k]; m0 = fmaf(w, Wdec[2*k], m0); m1 = fmaf(w, Wdec[2*k+1], m1); }
        ws[2*j] = m0; ws[2*j+1] = m1;
    } else if (tid < 1536) {                      // cgi
        int j = tid - 768; const float* wr = &W_ih[j * NH];
        float c = b_ih[j];
        for (int k = 0; k < NH; k++) c = fmaf(wr[k], bdec[k], c);
        ws[1536 + j] = c;
    } else if (tid < 1792) {                      // cA (SC-scaled except va)
        int h = tid - 1536; const float* war = &Wa[h * NH3];
        float as0 = 0.f, as1 = 0.f, ad1 = 0.f;
        for (int k = 0; k < NH; k++) {
            float w = war[k];
            as0 = fmaf(w, Ws[2*k], as0); as1 = fmaf(w, Ws[2*k+1], as1);
            ad1 = fmaf(war[NH + k], Wd[2*k+1], ad1);
        }
        float4 v = make_float4(SC*as0, SC*as1, SC*ad1, va[h]);
        ((float4*)(ws + 2304))[h] = v;
    } else if (tid < 2048) {                      // a0 (SC)
        int h = tid - 1792; const float* war = &Wa[h * NH3];
        float a = 0.f;
        for (int k = 0; k < NH; k++) {
            a = fmaf(war[k], bs[k], a);
            a = fmaf(war[NH + k], fmaf(20.0f, Wd[2*k], bd[k]), a);
        }
        ws[3328 + h] = SC * a;
    } else if (tid < 2304) {                      // cP (SC-scaled except vp)
        int h = tid - 2048; const float* wpr = &Wp[h * 2 * NH];
        float p0 = 0.f, p1 = 0.f;
        for (int k = 0; k < NH; k++) { float w = wpr[k]; p0 = fmaf(w, Ws[2*k], p0); p1 = fmaf(w, Ws[2*k+1], p1); }
        float4 v = make_float4(SC*p0, SC*p1, vp[h], 0.f);
        ((float4*)(ws + 3584))[h] = v;
    } else if (tid < 2560) {                      // cP2: SC*(PC0, PC1, pb)
        int h = tid - 2304;
        const float* wps = &Wp[h * 2 * NH];
        const float* wpc = wps + NH;
        float p0 = 0.f, p1 = 0.f, pb = 0.f;
        for (int k = 0; k < NH; k++) {
            p0 = fmaf(wpc[k], Ws[2*k], p0);
            p1 = fmaf(wpc[k], Ws[2*k+1], p1);
            pb = fmaf(wps[k] + wpc[k], bs[k], pb);
        }
        float4 v = make_float4(SC*p0, SC*p1, SC*pb, 0.f);
        ((float4*)(ws + 70912))[h] = v;
    } else if (tid < 2560 + 65536) {              // WaH pack (SC)
        int m = tid - 2560; int i = m >> 8, j = m & 255;
        ws[5376 + m] = SC * Wa[i * NH3 + 2 * NH + j];
    }
}

__global__ void __launch_bounds__(1024, 4)
drl_main(const float* __restrict__ gstatic, const float* __restrict__ gdyn,
         const float* __restrict__ glast, const float* __restrict__ gWhh,
         const float* __restrict__ gbhh, const float* __restrict__ wsb,
         float* __restrict__ out)
{
    __shared__ float s0[2][NN], s1[2][NN], d1[2][NN];
    __shared__ float hs[2][NH];
    __shared__ float ghs[2][NH3];
    __shared__ float qp[2][NH];
    __shared__ float4 cA[NH];
    __shared__ float4 cP[NH];
    __shared__ float4 cP2[NH];
    __shared__ float2 Mgi[NH3];
    __shared__ float cgi[NH3], bhh[NH3];
    __shared__ float a0v[NH];
    __shared__ float spart[2][NN * 9];     // 8 partials per n, stride 9
    __shared__ float Sw[2][2];
    __shared__ int idxs[2];

    const int t = threadIdx.x;
    const int g = t >> 9;          // batch elem within block
    const int r = t & 511;
    const int b0 = blockIdx.x * 2;

    // ---- stage inputs + coefficients into LDS
    for (int i = t; i < 2 * NN; i += 1024) {
        int gg = i >> 7, n = i & 127, b = b0 + gg;
        s0[gg][n] = gstatic[b * (NF * NN) + n];
        s1[gg][n] = gstatic[b * (NF * NN) + NN + n];
        d1[gg][n] = gdyn[b * (NF * NN) + NN + n];
    }
    for (int i = t; i < 2 * NH; i += 1024) {
        int gg = i >> 8, j = i & 255;
        hs[gg][j] = glast[(b0 + gg) * NH + j];
    }
    for (int i = t; i < 1536; i += 1024) ((float*)Mgi)[i] = wsb[i];
    if (t < 768) cgi[t] = wsb[1536 + t];
    if (t < 1024) ((float*)cA)[t] = wsb[2304 + t];
    if (t < 256) a0v[t] = wsb[3328 + t];
    if (t < 1024) ((float*)cP)[t] = wsb[3584 + t];
    if (t < 1024) ((float*)cP2)[t] = wsb[70912 + t];
    if (t < 768) bhh[t] = gbhh[t];
    if (t == 0) { idxs[0] = 0; idxs[1] = 0; }
    __syncthreads();

    const float* WaH = wsb + 5376;
    const int jb = t >> 3, kq = t & 7;     // fused-GEMV tiling: 128 rows, 8-way k-split
    const int jb2 = t >> 2, kh = t & 3;    // qp GEMV tiling: 256 rows, 4-way k-split

    // attention tiling: thread owns n-set {n0, n0+1}, h-set {hg + 8*hl, hl<32}
    const int ng = r >> 3, hg = r & 7;
    const int n0 = ng * 2;
    const float sv0a = s0[g][n0],     sv1a = s1[g][n0],     dva = d1[g][n0];
    const float sv0b = s0[g][n0 + 1], sv1b = s1[g][n0 + 1], dvb = d1[g][n0 + 1];
    float cwsum = 0.f, vpsum = 0.f;
    #pragma unroll 8
    for (int hl = 0; hl < 32; hl++) {
        cwsum += cA[hg + 8 * hl].w;
        vpsum += cP[hg + 8 * hl].z;
    }

    // ---- initial gh = W_hh*last_hh + b_hh (768 rows, 8-way k-split)
    {
        float acc[12];
        #pragma unroll
        for (int i = 0; i < 12; i++) acc[i] = 0.f;
        const float* wb = gWhh + jb * NH + 4 * kq;
        #pragma unroll 2
        for (int c = 0; c < 8; c++) {
            float4 h0 = *(const float4*)&hs[0][32 * c + 4 * kq];
            float4 h1 = *(const float4*)&hs[1][32 * c + 4 * kq];
            #pragma unroll
            for (int p = 0; p < 6; p++) {
                float4 w = *(const float4*)(wb + p * 128 * NH + 32 * c);
                acc[2*p]   = fmaf(w.x,h0.x,fmaf(w.y,h0.y,fmaf(w.z,h0.z,fmaf(w.w,h0.w,acc[2*p]))));
                acc[2*p+1] = fmaf(w.x,h1.x,fmaf(w.y,h1.y,fmaf(w.z,h1.z,fmaf(w.w,h1.w,acc[2*p+1]))));
            }
        }
        #pragma unroll
        for (int p = 0; p < 6; p++) {
            float u0 = acc[2*p], u1 = acc[2*p+1];
            u0 += __shfl_xor(u0, 1); u0 += __shfl_xor(u0, 2); u0 += __shfl_xor(u0, 4);
            u1 += __shfl_xor(u1, 1); u1 += __shfl_xor(u1, 2); u1 += __shfl_xor(u1, 4);
            if (kq == 0) { int j = jb + 128 * p; ghs[0][j] = u0 + bhh[j]; ghs[1][j] = u1 + bhh[j]; }
        }
    }
    __syncthreads();

    for (int step = 0; step < NN; step++) {
        // ---- P2: GRU elementwise (512 of 1024 threads active)
        if (r < 256) {
            int id = idxs[g];
            float svA = s0[g][id], svB = s1[g][id];
            float2 m0 = Mgi[r], m1 = Mgi[NH + r], m2 = Mgi[2 * NH + r];
            float ir  = fmaf(m0.x, svA, fmaf(m0.y, svB, cgi[r]));
            float iz  = fmaf(m1.x, svA, fmaf(m1.y, svB, cgi[NH + r]));
            float inn = fmaf(m2.x, svA, fmaf(m2.y, svB, cgi[2 * NH + r]));
            float rr = sigm(ir + ghs[g][r]);
            float zz = sigm(iz + ghs[g][NH + r]);
            float nv = tanh_raw(fmaf(rr, ghs[g][2 * NH + r], inn));
            float ho = hs[g][r];
            hs[g][r] = fmaf(zz, ho - nv, nv);
        }
        __syncthreads();
        // ---- B: qp = SC*Wa_h*h + a0  (256 rows x 2 batch, 4-way k-split)
        {
            float u0 = 0.f, u1 = 0.f;
            const float* wq = WaH + jb2 * NH + 4 * kh;
            #pragma unroll 4
            for (int ks = 0; ks < 16; ks++) {
                float4 w  = *(const float4*)(wq + ks * 16);
                float4 h0 = *(const float4*)&hs[0][ks * 16 + 4 * kh];
                float4 h1 = *(const float4*)&hs[1][ks * 16 + 4 * kh];
                u0 = fmaf(w.x,h0.x,fmaf(w.y,h0.y,fmaf(w.z,h0.z,fmaf(w.w,h0.w,u0))));
                u1 = fmaf(w.x,h1.x,fmaf(w.y,h1.y,fmaf(w.z,h1.z,fmaf(w.w,h1.w,u1))));
            }
            u0 += __shfl_xor(u0, 1); u0 += __shfl_xor(u0, 2);
            u1 += __shfl_xor(u1, 1); u1 += __shfl_xor(u1, 2);
            if (kh == 0) { qp[0][jb2] = u0 + a0v[jb2]; qp[1][jb2] = u1 + a0v[jb2]; }
        }
        __syncthreads();
        // ---- C: fused W_hh rows [0,384) GEMV + attention scan
        {
            float a0a = 0.f, a1a = 0.f, a2a = 0.f, a3a = 0.f, a4a = 0.f, a5a = 0.f;
            float at0 = cwsum, at1 = cwsum;
            const float* wb = gWhh + jb * NH + 4 * kq;
            #pragma unroll 1
            for (int ks = 0; ks < 8; ks++) {
                float4 w0 = *(const float4*)(wb + 0 * 128 * NH + ks * 32);
                float4 w1 = *(const float4*)(wb + 1 * 128 * NH + ks * 32);
                float4 w2 = *(const float4*)(wb + 2 * 128 * NH + ks * 32);
                #pragma unroll
                for (int u = 0; u < 4; u++) {
                    int h = hg + 8 * (4 * ks + u);
                    float4 c4 = cA[h];
                    float qv = qp[g][h];
                    float m2 = -2.f * c4.w;
                    float x0 = fmaf(c4.x, sv0a, fmaf(c4.y, sv1a, fmaf(c4.z, dva, qv)));
                    float x1 = fmaf(c4.x, sv0b, fmaf(c4.y, sv1b, fmaf(c4.z, dvb, qv)));
                    at0 = fmaf(m2, fast_rcp(1.0f + fast_exp2(x0)), at0);
                    at1 = fmaf(m2, fast_rcp(1.0f + fast_exp2(x1)), at1);
                }
                float4 h0 = *(const float4*)&hs[0][ks * 32 + 4 * kq];
                float4 h1 = *(const float4*)&hs[1][ks * 32 + 4 * kq];
                a0a = fmaf(w0.x,h0.x,fmaf(w0.y,h0.y,fmaf(w0.z,h0.z,fmaf(w0.w,h0.w,a0a))));
                a1a = fmaf(w0.x,h1.x,fmaf(w0.y,h1.y,fmaf(w0.z,h1.z,fmaf(w0.w,h1.w,a1a))));
                a2a = fmaf(w1.x,h0.x,fmaf(w1.y,h0.y,fmaf(w1.z,h0.z,fmaf(w1.w,h0.w,a2a))));
                a3a = fmaf(w1.x,h1.x,fmaf(w1.y,h1.y,fmaf(w1.z,h1.z,fmaf(w1.w,h1.w,a3a))));
                a4a = fmaf(w2.x,h0.x,fmaf(w2.y,h0.y,fmaf(w2.z,h0.z,fmaf(w2.w,h0.w,a4a))));
                a5a = fmaf(w2.x,h1.x,fmaf(w2.y,h1.y,fmaf(w2.z,h1.z,fmaf(w2.w,h1.w,a5a))));
            }
            spart[g][(n0 + 0) * 9 + hg] = at0;
            spart[g][(n0 + 1) * 9 + hg] = at1;
            a0a += __shfl_xor(a0a, 1); a0a += __shfl_xor(a0a, 2); a0a += __shfl_xor(a0a, 4);
            a1a += __shfl_xor(a1a, 1); a1a += __shfl_xor(a1a, 2); a1a += __shfl_xor(a1a, 4);
            a2a += __shfl_xor(a2a, 1); a2a += __shfl_xor(a2a, 2); a2a += __shfl_xor(a2a, 4);
            a3a += __shfl_xor(a3a, 1); a3a += __shfl_xor(a3a, 2); a3a += __shfl_xor(a3a, 4);
            a4a += __shfl_xor(a4a, 1); a4a += __shfl_xor(a4a, 2); a4a += __shfl_xor(a4a, 4);
            a5a += __shfl_xor(a5a, 1); a5a += __shfl_xor(a5a, 2); a5a += __shfl_xor(a5a, 4);
            if (kq == 0) {
                ghs[0][jb]       = a0a + bhh[jb];
                ghs[1][jb]       = a1a + bhh[jb];
                ghs[0][jb + 128] = a2a + bhh[jb + 128];
                ghs[1][jb + 128] = a3a + bhh[jb + 128];
                ghs[0][jb + 256] = a4a + bhh[jb + 256];
                ghs[1][jb + 256] = a5a + bhh[jb + 256];
            }
        }
        __syncthreads();
        // ---- P5: sum partials + softmax over n -> weighted sums S0w,S1w
        if (r < 64) {
            int l = r;
            float v0 = 0.f, v1 = 0.f;
            #pragma unroll
            for (int hq = 0; hq < 8; hq++) {
                v0 += spart[g][l * 9 + hq];
                v1 += spart[g][(l + 64) * 9 + hq];
            }
            float m = fmaxf(v0, v1);
            #pragma unroll
            for (int o = 32; o; o >>= 1) m = fmaxf(m, __shfl_xor(m, o));
            float e0 = __expf(v0 - m), e1 = __expf(v1 - m);
            float ss = e0 + e1;
            #pragma unroll
            for (int o = 32; o; o >>= 1) ss += __shfl_xor(ss, o);
            float rs = fast_rcp(ss);
            float w0 = e0 * rs, w1 = e1 * rs;
            float t0 = fmaf(w0, s0[g][l], w1 * s0[g][l + 64]);
            float t1 = fmaf(w0, s1[g][l], w1 * s1[g][l + 64]);
            #pragma unroll
            for (int o = 32; o; o >>= 1) { t0 += __shfl_xor(t0, o); t1 += __shfl_xor(t1, o); }
            if (l == 0) { Sw[g][0] = t0; Sw[g][1] = t1; }
        }
        __syncthreads();
        // ---- P7: fused W_hh rows [384,768) GEMV + pointer scan
        {
            float S0 = Sw[g][0], S1 = Sw[g][1];
            float a0a = 0.f, a1a = 0.f, a2a = 0.f, a3a = 0.f, a4a = 0.f, a5a = 0.f;
            float at0 = vpsum, at1 = vpsum;
            const float* wb = gWhh + (384 + jb) * NH + 4 * kq;
            #pragma unroll 1
            for (int ks = 0; ks < 8; ks++) {
                float4 w0 = *(const float4*)(wb + 0 * 128 * NH + ks * 32);
                float4 w1 = *(const float4*)(wb + 1 * 128 * NH + ks * 32);
                float4 w2 = *(const float4*)(wb + 2 * 128 * NH + ks * 32);
                #pragma unroll
                for (int u = 0; u < 4; u++) {
                    int h = hg + 8 * (4 * ks + u);
                    float4 c4 = cP[h];
                    float4 c2 = cP2[h];
                    float pc = fmaf(c2.x, S0, fmaf(c2.y, S1, c2.z));
                    float m2 = -2.f * c4.z;
                    float x0 = fmaf(c4.x, sv0a, fmaf(c4.y, sv1a, pc));
                    float x1 = fmaf(c4.x, sv0b, fmaf(c4.y, sv1b, pc));
                    at0 = fmaf(m2, fast_rcp(1.0f + fast_exp2(x0)), at0);
                    at1 = fmaf(m2, fast_rcp(1.0f + fast_exp2(x1)), at1);
                }
                float4 h0 = *(const float4*)&hs[0][ks * 32 + 4 * kq];
                float4 h1 = *(const float4*)&hs[1][ks * 32 + 4 * kq];
                a0a = fmaf(w0.x,h0.x,fmaf(w0.y,h0.y,fmaf(w0.z,h0.z,fmaf(w0.w,h0.w,a0a))));
                a1a = fmaf(w0.x,h1.x,fmaf(w0.y,h1.y,fmaf(w0.z,h1.z,fmaf(w0.w,h1.w,a1a))));
                a2a = fmaf(w1.x,h0.x,fmaf(w1.y,h0.y,fmaf(w1.z,h0.z,fmaf(w1.w,h0.w,a2a))));
                a3a = fmaf(w1.x,h1.x,fmaf(w1.y,h1.y,fmaf(w1.z,h1.z,fmaf(w1.w,h1.w,a3a))));
                a4a = fmaf(w2.x,h0.x,fmaf(w2.y,h0.y,fmaf(w2.z,h0.z,fmaf(w2.w,h0.w,a4a))));
                a5a = fmaf(w2.x,h1.x,fmaf(w2.y,h1.y,fmaf(w2.z,h1.z,fmaf(w2.w,h1.w,a5a))));
            }
            spart[g][(n0 + 0) * 9 + hg] = at0;
            spart[g][(n0 + 1) * 9 + hg] = at1;
            a0a += __shfl_xor(a0a, 1); a0a += __shfl_xor(a0a, 2); a0a += __shfl_xor(a0a, 4);
            a1a += __shfl_xor(a1a, 1); a1a += __shfl_xor(a1a, 2); a1a += __shfl_xor(a1a, 4);
            a2a += __shfl_xor(a2a, 1); a2a += __shfl_xor(a2a, 2); a2a += __shfl_xor(a2a, 4);
            a3a += __shfl_xor(a3a, 1); a3a += __shfl_xor(a3a, 2); a3a += __shfl_xor(a3a, 4);
            a4a += __shfl_xor(a4a, 1); a4a += __shfl_xor(a4a, 2); a4a += __shfl_xor(a4a, 4);
            a5a += __shfl_xor(a5a, 1); a5a += __shfl_xor(a5a, 2); a5a += __shfl_xor(a5a, 4);
            if (kq == 0) {
                ghs[0][384 + jb] = a0a + bhh[384 + jb];
                ghs[1][384 + jb] = a1a + bhh[384 + jb];
                ghs[0][512 + jb] = a2a + bhh[512 + jb];
                ghs[1][512 + jb] = a3a + bhh[512 + jb];
                ghs[0][640 + jb] = a4a + bhh[640 + jb];
                ghs[1][640 + jb] = a5a + bhh[640 + jb];
            }
        }
        __syncthreads();
        // ---- P8: sum partials + softmax + argmax (first-index tiebreak) + outputs
        if (r < 64) {
            int l = r;
            float v0 = 0.f, v1 = 0.f;
            #pragma unroll
            for (int hq = 0; hq < 8; hq++) {
                v0 += spart[g][l * 9 + hq];
                v1 += spart[g][(l + 64) * 9 + hq];
            }
            float bv = v0; int bi = l;
            if (v1 > v0) { bv = v1; bi = l + 64; }
            #pragma unroll
            for (int o = 32; o; o >>= 1) {
                float ov = __shfl_xor(bv, o); int oi = __shfl_xor(bi, o);
                if (ov > bv || (ov == bv && oi < bi)) { bv = ov; bi = oi; }
            }
            float e0 = __expf(v0 - bv), e1 = __expf(v1 - bv);
            float ss = e0 + e1;
            #pragma unroll
            for (int o = 32; o; o >>= 1) ss += __shfl_xor(ss, o);
            if (l == 0) {
                idxs[g] = bi;
                int b = b0 + g;
                out[b * NN + step] = (float)bi;
                out[NB * NN + b * NN + step] = -logf(ss);
            }
        }
        __syncthreads();
    }
}

extern "C" void kernel_launch(void* const* d_in, const int* in_sizes, int n_in,
                              void* d_out, int out_size, void* d_ws, size_t ws_size,
                              hipStream_t stream) {
    const float* gstatic = (const float*)d_in[0];
    const float* gdyn    = (const float*)d_in[1];
    const float* glast   = (const float*)d_in[2];
    const float* Ws      = (const float*)d_in[3];
    const float* bs      = (const float*)d_in[4];
    const float* Wd      = (const float*)d_in[5];
    const float* bd      = (const float*)d_in[6];
    const float* Wdec    = (const float*)d_in[7];
    const float* bdec    = (const float*)d_in[8];
    const float* W_ih    = (const float*)d_in[9];
    const float* W_hh    = (const float*)d_in[10];
    const float* b_ih    = (const float*)d_in[11];
    const float* b_hh    = (const float*)d_in[12];
    const float* Wa      = (const float*)d_in[13];
    const float* va      = (const float*)d_in[14];
    const float* Wp      = (const float*)d_in[15];
    const float* vp      = (const float*)d_in[16];
    float* outp = (float*)d_out;
    float* wsb  = (float*)d_ws;

    // 2560 coefficient dots + 65536 WaH pack = 68096 tasks
    precompute_kernel<<<267, 256, 0, stream>>>(Ws, bs, Wd, bd, Wdec, bdec,
                                               W_ih, b_ih, Wa, va, Wp, vp, wsb);
    drl_main<<<256, 1024, 0, stream>>>(gstatic, gdyn, glast, W_hh, b_hh, wsb, outp);
}

// Round 6
// 2118.204 us; speedup vs baseline: 3.4925x; 1.0700x over previous
//
#include <hip/hip_runtime.h>
#include <math.h>

// DRL4TSP decode: B=512, F=2, N=128, H=256, 128 steps.
// R6: VALU-issue bound (busy-cycles invariant R4->R5 at ~37K/step). Cut issue
// slots: (a) v_pk_fma_f32 packed fp32 via ext_vector_type(2) — scans pack the
// 2 n-values per thread, GEMVs pack the 2 batch elems (hs stored interleaved);
// (b) shared-rcp: 1/t0 and 1/t1 from one rcp(t0*t1) — halves rcp count.
// Structure/phases identical to R5. No local arrays with dynamic indices.

#define NB 512
#define NF 2
#define NN 128
#define NH 256
#define NH3 768
#define SC 2.8853900817779268f   // 2*log2(e): folds tanh doubling + exp->exp2

typedef float v2f __attribute__((ext_vector_type(2)));

__device__ __forceinline__ float fast_rcp(float x) { return __builtin_amdgcn_rcpf(x); }
__device__ __forceinline__ float fast_exp2(float x) { return __builtin_amdgcn_exp2f(x); }
__device__ __forceinline__ float sigm(float x) { return fast_rcp(1.0f + __expf(-x)); }
__device__ __forceinline__ float tanh_raw(float x) { return 1.0f - 2.0f * fast_rcp(1.0f + fast_exp2(SC * x)); }
__device__ __forceinline__ v2f vsplat(float a) { v2f r; r.x = a; r.y = a; return r; }
__device__ __forceinline__ v2f vfma(v2f a, v2f b, v2f c) { return __builtin_elementwise_fma(a, b, c); }

// ws layout (floats):
//   0     : Mgi[768] float2   (W_ih·Wdec, 2 cols interleaved)   [unscaled]
//   1536  : cgi[768]          (W_ih·bdec + b_ih)                [unscaled]
//   2304  : cA[256] float4    (SC*A_s0, SC*A_s1, SC*A_d1, va)
//   3328  : a0[256]           (SC*(Wa_s·bs + Wa_d·(20*Wd0+bd)))
//   3584  : cP[256] float4    (SC*P_s0, SC*P_s1, vp, 0)
//   5376  : WaH[256*256]      (SC*Wa[:,2H:3H] row-major)
//   70912 : cP2[256] float4   (SC*PC0, SC*PC1, SC*pb, 0)

__global__ void precompute_kernel(const float* __restrict__ Ws, const float* __restrict__ bs,
                                  const float* __restrict__ Wd, const float* __restrict__ bd,
                                  const float* __restrict__ Wdec, const float* __restrict__ bdec,
                                  const float* __restrict__ W_ih, const float* __restrict__ b_ih,
                                  const float* __restrict__ Wa, const float* __restrict__ va,
                                  const float* __restrict__ Wp, const float* __restrict__ vp,
                                  float* __restrict__ ws)
{
    int tid = blockIdx.x * blockDim.x + threadIdx.x;
    if (tid < 768) {                              // Mgi
        int j = tid; const float* wr = &W_ih[j * NH];
        float m0 = 0.f, m1 = 0.f;
        for (int k = 0; k < NH; k++) { float w = wr[k]; m0 = fmaf(w, Wdec[2*k], m0); m1 = fmaf(w, Wdec[2*k+1], m1); }
        ws[2*j] = m0; ws[2*j+1] = m1;
    } else if (tid < 1536) {                      // cgi
        int j = tid - 768; const float* wr = &W_ih[j * NH];
        float c = b_ih[j];
        for (int k = 0; k < NH; k++) c = fmaf(wr[k], bdec[k], c);
        ws[1536 + j] = c;
    } else if (tid < 1792) {                      // cA (SC-scaled except va)
        int h = tid - 1536; const float* war = &Wa[h * NH3];
        float as0 = 0.f, as1 = 0.f, ad1 = 0.f;
        for (int k = 0; k < NH; k++) {
            float w = war[k];
            as0 = fmaf(w, Ws[2*k], as0); as1 = fmaf(w, Ws[2*k+1], as1);
            ad1 = fmaf(war[NH + k], Wd[2*k+1], ad1);
        }
        float4 v = make_float4(SC*as0, SC*as1, SC*ad1, va[h]);
        ((float4*)(ws + 2304))[h] = v;
    } else if (tid < 2048) {                      // a0 (SC)
        int h = tid - 1792; const float* war = &Wa[h * NH3];
        float a = 0.f;
        for (int k = 0; k < NH; k++) {
            a = fmaf(war[k], bs[k], a);
            a = fmaf(war[NH + k], fmaf(20.0f, Wd[2*k], bd[k]), a);
        }
        ws[3328 + h] = SC * a;
    } else if (tid < 2304) {                      // cP (SC-scaled except vp)
        int h = tid - 2048; const float* wpr = &Wp[h * 2 * NH];
        float p0 = 0.f, p1 = 0.f;
        for (int k = 0; k < NH; k++) { float w = wpr[k]; p0 = fmaf(w, Ws[2*k], p0); p1 = fmaf(w, Ws[2*k+1], p1); }
        float4 v = make_float4(SC*p0, SC*p1, vp[h], 0.f);
        ((float4*)(ws + 3584))[h] = v;
    } else if (tid < 2560) {                      // cP2: SC*(PC0, PC1, pb)
        int h = tid - 2304;
        const float* wps = &Wp[h * 2 * NH];
        const float* wpc = wps + NH;
        float p0 = 0.f, p1 = 0.f, pb = 0.f;
        for (int k = 0; k < NH; k++) {
            p0 = fmaf(wpc[k], Ws[2*k], p0);
            p1 = fmaf(wpc[k], Ws[2*k+1], p1);
            pb = fmaf(wps[k] + wpc[k], bs[k], pb);
        }
        float4 v = make_float4(SC*p0, SC*p1, SC*pb, 0.f);
        ((float4*)(ws + 70912))[h] = v;
    } else if (tid < 2560 + 65536) {              // WaH pack (SC)
        int m = tid - 2560; int i = m >> 8, j = m & 255;
        ws[5376 + m] = SC * Wa[i * NH3 + 2 * NH + j];
    }
}

__global__ void __launch_bounds__(1024, 4)
drl_main(const float* __restrict__ gstatic, const float* __restrict__ gdyn,
         const float* __restrict__ glast, const float* __restrict__ gWhh,
         const float* __restrict__ gbhh, const float* __restrict__ wsb,
         float* __restrict__ out)
{
    __shared__ float s0[2][NN], s1[2][NN], d1[2][NN];
    __shared__ v2f hs2[NH];                // h interleaved over batch: (g0,g1)
    __shared__ float ghs[2][NH3];
    __shared__ float qp[2][NH];
    __shared__ float4 cA[NH];
    __shared__ float4 cP[NH];
    __shared__ float4 cP2[NH];
    __shared__ float2 Mgi[NH3];
    __shared__ float cgi[NH3], bhh[NH3];
    __shared__ float a0v[NH];
    __shared__ float spart[2][NN * 9];     // 8 partials per n, stride 9
    __shared__ float Sw[2][2];
    __shared__ int idxs[2];

    const int t = threadIdx.x;
    const int g = t >> 9;          // batch elem within block
    const int r = t & 511;
    const int b0 = blockIdx.x * 2;

    // ---- stage inputs + coefficients into LDS
    for (int i = t; i < 2 * NN; i += 1024) {
        int gg = i >> 7, n = i & 127, b = b0 + gg;
        s0[gg][n] = gstatic[b * (NF * NN) + n];
        s1[gg][n] = gstatic[b * (NF * NN) + NN + n];
        d1[gg][n] = gdyn[b * (NF * NN) + NN + n];
    }
    for (int i = t; i < 2 * NH; i += 1024) {
        int gg = i >> 8, j = i & 255;
        ((float*)hs2)[2 * j + gg] = glast[(b0 + gg) * NH + j];
    }
    for (int i = t; i < 1536; i += 1024) ((float*)Mgi)[i] = wsb[i];
    if (t < 768) cgi[t] = wsb[1536 + t];
    if (t < 1024) ((float*)cA)[t] = wsb[2304 + t];
    if (t < 256) a0v[t] = wsb[3328 + t];
    if (t < 1024) ((float*)cP)[t] = wsb[3584 + t];
    if (t < 1024) ((float*)cP2)[t] = wsb[70912 + t];
    if (t < 768) bhh[t] = gbhh[t];
    if (t == 0) { idxs[0] = 0; idxs[1] = 0; }
    __syncthreads();

    const float* WaH = wsb + 5376;
    const int jb = t >> 3, kq = t & 7;     // fused-GEMV tiling: 128 rows, 8-way k-split
    const int jb2 = t >> 2, kh = t & 3;    // qp GEMV tiling: 256 rows, 4-way k-split

    // attention tiling: thread owns n-pair {n0, n0+1} packed, h-set {hg + 8*hl}
    const int ng = r >> 3, hg = r & 7;
    const int n0 = ng * 2;
    v2f sv0, sv1, dvv;
    sv0.x = s0[g][n0]; sv0.y = s0[g][n0 + 1];
    sv1.x = s1[g][n0]; sv1.y = s1[g][n0 + 1];
    dvv.x = d1[g][n0]; dvv.y = d1[g][n0 + 1];
    float cwsum = 0.f, vpsum = 0.f;
    #pragma unroll 8
    for (int hl = 0; hl < 32; hl++) {
        cwsum += cA[hg + 8 * hl].w;
        vpsum += cP[hg + 8 * hl].z;
    }

    // ---- initial gh = W_hh*last_hh + b_hh (768 rows, 8-way k-split, batch-packed)
    {
        v2f acc[6];
        #pragma unroll
        for (int i = 0; i < 6; i++) { acc[i].x = 0.f; acc[i].y = 0.f; }
        const float* wb = gWhh + jb * NH + 4 * kq;
        #pragma unroll 2
        for (int c = 0; c < 8; c++) {
            float4 p01 = *(const float4*)&((float*)hs2)[2 * (32 * c + 4 * kq)];
            float4 p23 = *(const float4*)&((float*)hs2)[2 * (32 * c + 4 * kq) + 4];
            v2f hk0, hk1, hk2, hk3;
            hk0.x = p01.x; hk0.y = p01.y; hk1.x = p01.z; hk1.y = p01.w;
            hk2.x = p23.x; hk2.y = p23.y; hk3.x = p23.z; hk3.y = p23.w;
            #pragma unroll
            for (int p = 0; p < 6; p++) {
                float4 w = *(const float4*)(wb + p * 128 * NH + 32 * c);
                acc[p] = vfma(vsplat(w.x), hk0, vfma(vsplat(w.y), hk1,
                         vfma(vsplat(w.z), hk2, vfma(vsplat(w.w), hk3, acc[p]))));
            }
        }
        #pragma unroll
        for (int p = 0; p < 6; p++) {
            float u0 = acc[p].x, u1 = acc[p].y;
            u0 += __shfl_xor(u0, 1); u0 += __shfl_xor(u0, 2); u0 += __shfl_xor(u0, 4);
            u1 += __shfl_xor(u1, 1); u1 += __shfl_xor(u1, 2); u1 += __shfl_xor(u1, 4);
            if (kq == 0) { int j = jb + 128 * p; ghs[0][j] = u0 + bhh[j]; ghs[1][j] = u1 + bhh[j]; }
        }
    }
    __syncthreads();

    for (int step = 0; step < NN; step++) {
        // ---- P2: GRU elementwise (512 of 1024 threads active)
        if (r < 256) {
            int id = idxs[g];
            float svA = s0[g][id], svB = s1[g][id];
            float2 m0 = Mgi[r], m1 = Mgi[NH + r], m2 = Mgi[2 * NH + r];
            float ir  = fmaf(m0.x, svA, fmaf(m0.y, svB, cgi[r]));
            float iz  = fmaf(m1.x, svA, fmaf(m1.y, svB, cgi[NH + r]));
            float inn = fmaf(m2.x, svA, fmaf(m2.y, svB, cgi[2 * NH + r]));
            float rr = sigm(ir + ghs[g][r]);
            float zz = sigm(iz + ghs[g][NH + r]);
            float nv = tanh_raw(fmaf(rr, ghs[g][2 * NH + r], inn));
            float ho = ((float*)hs2)[2 * r + g];
            ((float*)hs2)[2 * r + g] = fmaf(zz, ho - nv, nv);
        }
        __syncthreads();
        // ---- B: qp = SC*Wa_h*h + a0  (256 rows, 4-way k-split, batch-packed)
        {
            v2f u; u.x = 0.f; u.y = 0.f;
            const float* wq = WaH + jb2 * NH + 4 * kh;
            #pragma unroll 4
            for (int ks = 0; ks < 16; ks++) {
                float4 w  = *(const float4*)(wq + ks * 16);
                float4 p01 = *(const float4*)&((float*)hs2)[2 * (ks * 16 + 4 * kh)];
                float4 p23 = *(const float4*)&((float*)hs2)[2 * (ks * 16 + 4 * kh) + 4];
                v2f hk0, hk1, hk2, hk3;
                hk0.x = p01.x; hk0.y = p01.y; hk1.x = p01.z; hk1.y = p01.w;
                hk2.x = p23.x; hk2.y = p23.y; hk3.x = p23.z; hk3.y = p23.w;
                u = vfma(vsplat(w.x), hk0, vfma(vsplat(w.y), hk1,
                    vfma(vsplat(w.z), hk2, vfma(vsplat(w.w), hk3, u))));
            }
            u.x += __shfl_xor(u.x, 1); u.x += __shfl_xor(u.x, 2);
            u.y += __shfl_xor(u.y, 1); u.y += __shfl_xor(u.y, 2);
            if (kh == 0) { qp[0][jb2] = u.x + a0v[jb2]; qp[1][jb2] = u.y + a0v[jb2]; }
        }
        __syncthreads();
        // ---- C: fused W_hh rows [0,384) GEMV + attention scan (both packed)
        {
            v2f at = vsplat(cwsum);
            v2f g0, g1, g2;
            g0.x = 0.f; g0.y = 0.f; g1.x = 0.f; g1.y = 0.f; g2.x = 0.f; g2.y = 0.f;
            const float* wb = gWhh + jb * NH + 4 * kq;
            #pragma unroll 1
            for (int ks = 0; ks < 8; ks++) {
                float4 w0 = *(const float4*)(wb + 0 * 128 * NH + ks * 32);
                float4 w1 = *(const float4*)(wb + 1 * 128 * NH + ks * 32);
                float4 w2 = *(const float4*)(wb + 2 * 128 * NH + ks * 32);
                #pragma unroll
                for (int u = 0; u < 4; u++) {
                    int h = hg + 8 * (4 * ks + u);
                    float4 c4 = cA[h];
                    float qv = qp[g][h];
                    v2f x = vfma(vsplat(c4.x), sv0, vfma(vsplat(c4.y), sv1,
                            vfma(vsplat(c4.z), dvv, vsplat(qv))));
                    v2f e; e.x = fast_exp2(x.x); e.y = fast_exp2(x.y);
                    v2f tt = e + 1.0f;
                    float rd = fast_rcp(tt.x * tt.y);
                    float mm = -2.0f * c4.w * rd;
                    at = vfma(vsplat(mm), tt.yx, at);   // at.x += mm*t1, at.y += mm*t0
                }
                float4 p01 = *(const float4*)&((float*)hs2)[2 * (ks * 32 + 4 * kq)];
                float4 p23 = *(const float4*)&((float*)hs2)[2 * (ks * 32 + 4 * kq) + 4];
                v2f hk0, hk1, hk2, hk3;
                hk0.x = p01.x; hk0.y = p01.y; hk1.x = p01.z; hk1.y = p01.w;
                hk2.x = p23.x; hk2.y = p23.y; hk3.x = p23.z; hk3.y = p23.w;
                g0 = vfma(vsplat(w0.x), hk0, vfma(vsplat(w0.y), hk1,
                     vfma(vsplat(w0.z), hk2, vfma(vsplat(w0.w), hk3, g0))));
                g1 = vfma(vsplat(w1.x), hk0, vfma(vsplat(w1.y), hk1,
                     vfma(vsplat(w1.z), hk2, vfma(vsplat(w1.w), hk3, g1))));
                g2 = vfma(vsplat(w2.x), hk0, vfma(vsplat(w2.y), hk1,
                     vfma(vsplat(w2.z), hk2, vfma(vsplat(w2.w), hk3, g2))));
            }
            spart[g][(n0 + 0) * 9 + hg] = at.x;
            spart[g][(n0 + 1) * 9 + hg] = at.y;
            g0.x += __shfl_xor(g0.x, 1); g0.x += __shfl_xor(g0.x, 2); g0.x += __shfl_xor(g0.x, 4);
            g0.y += __shfl_xor(g0.y, 1); g0.y += __shfl_xor(g0.y, 2); g0.y += __shfl_xor(g0.y, 4);
            g1.x += __shfl_xor(g1.x, 1); g1.x += __shfl_xor(g1.x, 2); g1.x += __shfl_xor(g1.x, 4);
            g1.y += __shfl_xor(g1.y, 1); g1.y += __shfl_xor(g1.y, 2); g1.y += __shfl_xor(g1.y, 4);
            g2.x += __shfl_xor(g2.x, 1); g2.x += __shfl_xor(g2.x, 2); g2.x += __shfl_xor(g2.x, 4);
            g2.y += __shfl_xor(g2.y, 1); g2.y += __shfl_xor(g2.y, 2); g2.y += __shfl_xor(g2.y, 4);
            if (kq == 0) {
                ghs[0][jb]       = g0.x + bhh[jb];
                ghs[1][jb]       = g0.y + bhh[jb];
                ghs[0][jb + 128] = g1.x + bhh[jb + 128];
                ghs[1][jb + 128] = g1.y + bhh[jb + 128];
                ghs[0][jb + 256] = g2.x + bhh[jb + 256];
                ghs[1][jb + 256] = g2.y + bhh[jb + 256];
            }
        }
        __syncthreads();
        // ---- P5: sum partials + softmax over n -> weighted sums S0w,S1w
        if (r < 64) {
            int l = r;
            float v0 = 0.f, v1 = 0.f;
            #pragma unroll
            for (int hq = 0; hq < 8; hq++) {
                v0 += spart[g][l * 9 + hq];
                v1 += spart[g][(l + 64) * 9 + hq];
            }
            float m = fmaxf(v0, v1);
            #pragma unroll
            for (int o = 32; o; o >>= 1) m = fmaxf(m, __shfl_xor(m, o));
            float e0 = __expf(v0 - m), e1 = __expf(v1 - m);
            float ss = e0 + e1;
            #pragma unroll
            for (int o = 32; o; o >>= 1) ss += __shfl_xor(ss, o);
            float rs = fast_rcp(ss);
            float w0 = e0 * rs, w1 = e1 * rs;
            float t0 = fmaf(w0, s0[g][l], w1 * s0[g][l + 64]);
            float t1 = fmaf(w0, s1[g][l], w1 * s1[g][l + 64]);
            #pragma unroll
            for (int o = 32; o; o >>= 1) { t0 += __shfl_xor(t0, o); t1 += __shfl_xor(t1, o); }
            if (l == 0) { Sw[g][0] = t0; Sw[g][1] = t1; }
        }
        __syncthreads();
        // ---- P7: fused W_hh rows [384,768) GEMV + pointer scan (both packed)
        {
            float S0 = Sw[g][0], S1 = Sw[g][1];
            v2f at = vsplat(vpsum);
            v2f g0, g1, g2;
            g0.x = 0.f; g0.y = 0.f; g1.x = 0.f; g1.y = 0.f; g2.x = 0.f; g2.y = 0.f;
            const float* wb = gWhh + (384 + jb) * NH + 4 * kq;
            #pragma unroll 1
            for (int ks = 0; ks < 8; ks++) {
                float4 w0 = *(const float4*)(wb + 0 * 128 * NH + ks * 32);
                float4 w1 = *(const float4*)(wb + 1 * 128 * NH + ks * 32);
                float4 w2 = *(const float4*)(wb + 2 * 128 * NH + ks * 32);
                #pragma unroll
                for (int u = 0; u < 4; u++) {
                    int h = hg + 8 * (4 * ks + u);
                    float4 c4 = cP[h];
                    float4 c2 = cP2[h];
                    float pc = fmaf(c2.x, S0, fmaf(c2.y, S1, c2.z));
                    v2f x = vfma(vsplat(c4.x), sv0, vfma(vsplat(c4.y), sv1, vsplat(pc)));
                    v2f e; e.x = fast_exp2(x.x); e.y = fast_exp2(x.y);
                    v2f tt = e + 1.0f;
                    float rd = fast_rcp(tt.x * tt.y);
                    float mm = -2.0f * c4.z * rd;
                    at = vfma(vsplat(mm), tt.yx, at);
                }
                float4 p01 = *(const float4*)&((float*)hs2)[2 * (ks * 32 + 4 * kq)];
                float4 p23 = *(const float4*)&((float*)hs2)[2 * (ks * 32 + 4 * kq) + 4];
                v2f hk0, hk1, hk2, hk3;
                hk0.x = p01.x; hk0.y = p01.y; hk1.x = p01.z; hk1.y = p01.w;
                hk2.x = p23.x; hk2.y = p23.y; hk3.x = p23.z; hk3.y = p23.w;
                g0 = vfma(vsplat(w0.x), hk0, vfma(vsplat(w0.y), hk1,
                     vfma(vsplat(w0.z), hk2, vfma(vsplat(w0.w), hk3, g0))));
                g1 = vfma(vsplat(w1.x), hk0, vfma(vsplat(w1.y), hk1,
                     vfma(vsplat(w1.z), hk2, vfma(vsplat(w1.w), hk3, g1))));
                g2 = vfma(vsplat(w2.x), hk0, vfma(vsplat(w2.y), hk1,
                     vfma(vsplat(w2.z), hk2, vfma(vsplat(w2.w), hk3, g2))));
            }
            spart[g][(n0 + 0) * 9 + hg] = at.x;
            spart[g][(n0 + 1) * 9 + hg] = at.y;
            g0.x += __shfl_xor(g0.x, 1); g0.x += __shfl_xor(g0.x, 2); g0.x += __shfl_xor(g0.x, 4);
            g0.y += __shfl_xor(g0.y, 1); g0.y += __shfl_xor(g0.y, 2); g0.y += __shfl_xor(g0.y, 4);
            g1.x += __shfl_xor(g1.x, 1); g1.x += __shfl_xor(g1.x, 2); g1.x += __shfl_xor(g1.x, 4);
            g1.y += __shfl_xor(g1.y, 1); g1.y += __shfl_xor(g1.y, 2); g1.y += __shfl_xor(g1.y, 4);
            g2.x += __shfl_xor(g2.x, 1); g2.x += __shfl_xor(g2.x, 2); g2.x += __shfl_xor(g2.x, 4);
            g2.y += __shfl_xor(g2.y, 1); g2.y += __shfl_xor(g2.y, 2); g2.y += __shfl_xor(g2.y, 4);
            if (kq == 0) {
                ghs[0][384 + jb] = g0.x + bhh[384 + jb];
                ghs[1][384 + jb] = g0.y + bhh[384 + jb];
                ghs[0][512 + jb] = g1.x + bhh[512 + jb];
                ghs[1][512 + jb] = g1.y + bhh[512 + jb];
                ghs[0][640 + jb] = g2.x + bhh[640 + jb];
                ghs[1][640 + jb] = g2.y + bhh[640 + jb];
            }
        }
        __syncthreads();
        // ---- P8: sum partials + softmax + argmax (first-index tiebreak) + outputs
        if (r < 64) {
            int l = r;
            float v0 = 0.f, v1 = 0.f;
            #pragma unroll
            for (int hq = 0; hq < 8; hq++) {
                v0 += spart[g][l * 9 + hq];
                v1 += spart[g][(l + 64) * 9 + hq];
            }
            float bv = v0; int bi = l;
            if (v1 > v0) { bv = v1; bi = l + 64; }
            #pragma unroll
            for (int o = 32; o; o >>= 1) {
                float ov = __shfl_xor(bv, o); int oi = __shfl_xor(bi, o);
                if (ov > bv || (ov == bv && oi < bi)) { bv = ov; bi = oi; }
            }
            float e0 = __expf(v0 - bv), e1 = __expf(v1 - bv);
            float ss = e0 + e1;
            #pragma unroll
            for (int o = 32; o; o >>= 1) ss += __shfl_xor(ss, o);
            if (l == 0) {
                idxs[g] = bi;
                int b = b0 + g;
                out[b * NN + step] = (float)bi;
                out[NB * NN + b * NN + step] = -logf(ss);
            }
        }
        __syncthreads();
    }
}

extern "C" void kernel_launch(void* const* d_in, const int* in_sizes, int n_in,
                              void* d_out, int out_size, void* d_ws, size_t ws_size,
                              hipStream_t stream) {
    const float* gstatic = (const float*)d_in[0];
    const float* gdyn    = (const float*)d_in[1];
    const float* glast   = (const float*)d_in[2];
    const float* Ws      = (const float*)d_in[3];
    const float* bs      = (const float*)d_in[4];
    const float* Wd      = (const float*)d_in[5];
    const float* bd      = (const float*)d_in[6];
    const float* Wdec    = (const float*)d_in[7];
    const float* bdec    = (const float*)d_in[8];
    const float* W_ih    = (const float*)d_in[9];
    const float* W_hh    = (const float*)d_in[10];
    const float* b_ih    = (const float*)d_in[11];
    const float* b_hh    = (const float*)d_in[12];
    const float* Wa      = (const float*)d_in[13];
    const float* va      = (const float*)d_in[14];
    const float* Wp      = (const float*)d_in[15];
    const float* vp      = (const float*)d_in[16];
    float* outp = (float*)d_out;
    float* wsb  = (float*)d_ws;

    precompute_kernel<<<267, 256, 0, stream>>>(Ws, bs, Wd, bd, Wdec, bdec,
                                               W_ih, b_ih, Wa, va, Wp, vp, wsb);
    drl_main<<<256, 1024, 0, stream>>>(gstatic, gdyn, glast, W_hh, b_hh, wsb, outp);
}

// Round 7
// 2075.837 us; speedup vs baseline: 3.5638x; 1.0204x over previous
//
#include <hip/hip_runtime.h>
#include <math.h>

// DRL4TSP decode: B=512, F=2, N=128, H=256, 128 steps.
// R7: scan remap 8hg x 64ng -> 16hg x 32ng (16 h x 4 n per thread, two packed
// pairs) halves scan LDS instructions (cA/cP/qp amortize over 4 evals);
// 4-way shared rcp (one rcp per 4 tanh evals); -2 folded into cA.w/cP.z.
// Phases/barriers identical to R6. No local arrays with dynamic indices.

#define NB 512
#define NF 2
#define NN 128
#define NH 256
#define NH3 768
#define SC 2.8853900817779268f   // 2*log2(e): folds tanh doubling + exp->exp2

typedef float v2f __attribute__((ext_vector_type(2)));

__device__ __forceinline__ float fast_rcp(float x) { return __builtin_amdgcn_rcpf(x); }
__device__ __forceinline__ float fast_exp2(float x) { return __builtin_amdgcn_exp2f(x); }
__device__ __forceinline__ float sigm(float x) { return fast_rcp(1.0f + __expf(-x)); }
__device__ __forceinline__ float tanh_raw(float x) { return 1.0f - 2.0f * fast_rcp(1.0f + fast_exp2(SC * x)); }
__device__ __forceinline__ v2f vsplat(float a) { v2f r; r.x = a; r.y = a; return r; }
__device__ __forceinline__ v2f vfma(v2f a, v2f b, v2f c) { return __builtin_elementwise_fma(a, b, c); }

// ws layout (floats):
//   0     : Mgi[768] float2   (W_ih·Wdec, 2 cols interleaved)   [unscaled]
//   1536  : cgi[768]          (W_ih·bdec + b_ih)                [unscaled]
//   2304  : cA[256] float4    (SC*A_s0, SC*A_s1, SC*A_d1, -2*va)
//   3328  : a0[256]           (SC*(Wa_s·bs + Wa_d·(20*Wd0+bd)))
//   3584  : cP[256] float4    (SC*P_s0, SC*P_s1, -2*vp, 0)
//   5376  : WaH[256*256]      (SC*Wa[:,2H:3H] row-major)
//   70912 : cP2[256] float4   (SC*PC0, SC*PC1, SC*pb, 0)

__global__ void precompute_kernel(const float* __restrict__ Ws, const float* __restrict__ bs,
                                  const float* __restrict__ Wd, const float* __restrict__ bd,
                                  const float* __restrict__ Wdec, const float* __restrict__ bdec,
                                  const float* __restrict__ W_ih, const float* __restrict__ b_ih,
                                  const float* __restrict__ Wa, const float* __restrict__ va,
                                  const float* __restrict__ Wp, const float* __restrict__ vp,
                                  float* __restrict__ ws)
{
    int tid = blockIdx.x * blockDim.x + threadIdx.x;
    if (tid < 768) {                              // Mgi
        int j = tid; const float* wr = &W_ih[j * NH];
        float m0 = 0.f, m1 = 0.f;
        for (int k = 0; k < NH; k++) { float w = wr[k]; m0 = fmaf(w, Wdec[2*k], m0); m1 = fmaf(w, Wdec[2*k+1], m1); }
        ws[2*j] = m0; ws[2*j+1] = m1;
    } else if (tid < 1536) {                      // cgi
        int j = tid - 768; const float* wr = &W_ih[j * NH];
        float c = b_ih[j];
        for (int k = 0; k < NH; k++) c = fmaf(wr[k], bdec[k], c);
        ws[1536 + j] = c;
    } else if (tid < 1792) {                      // cA (SC-scaled; .w = -2*va)
        int h = tid - 1536; const float* war = &Wa[h * NH3];
        float as0 = 0.f, as1 = 0.f, ad1 = 0.f;
        for (int k = 0; k < NH; k++) {
            float w = war[k];
            as0 = fmaf(w, Ws[2*k], as0); as1 = fmaf(w, Ws[2*k+1], as1);
            ad1 = fmaf(war[NH + k], Wd[2*k+1], ad1);
        }
        float4 v = make_float4(SC*as0, SC*as1, SC*ad1, -2.0f*va[h]);
        ((float4*)(ws + 2304))[h] = v;
    } else if (tid < 2048) {                      // a0 (SC)
        int h = tid - 1792; const float* war = &Wa[h * NH3];
        float a = 0.f;
        for (int k = 0; k < NH; k++) {
            a = fmaf(war[k], bs[k], a);
            a = fmaf(war[NH + k], fmaf(20.0f, Wd[2*k], bd[k]), a);
        }
        ws[3328 + h] = SC * a;
    } else if (tid < 2304) {                      // cP (SC-scaled; .z = -2*vp)
        int h = tid - 2048; const float* wpr = &Wp[h * 2 * NH];
        float p0 = 0.f, p1 = 0.f;
        for (int k = 0; k < NH; k++) { float w = wpr[k]; p0 = fmaf(w, Ws[2*k], p0); p1 = fmaf(w, Ws[2*k+1], p1); }
        float4 v = make_float4(SC*p0, SC*p1, -2.0f*vp[h], 0.f);
        ((float4*)(ws + 3584))[h] = v;
    } else if (tid < 2560) {                      // cP2: SC*(PC0, PC1, pb)
        int h = tid - 2304;
        const float* wps = &Wp[h * 2 * NH];
        const float* wpc = wps + NH;
        float p0 = 0.f, p1 = 0.f, pb = 0.f;
        for (int k = 0; k < NH; k++) {
            p0 = fmaf(wpc[k], Ws[2*k], p0);
            p1 = fmaf(wpc[k], Ws[2*k+1], p1);
            pb = fmaf(wps[k] + wpc[k], bs[k], pb);
        }
        float4 v = make_float4(SC*p0, SC*p1, SC*pb, 0.f);
        ((float4*)(ws + 70912))[h] = v;
    } else if (tid < 2560 + 65536) {              // WaH pack (SC)
        int m = tid - 2560; int i = m >> 8, j = m & 255;
        ws[5376 + m] = SC * Wa[i * NH3 + 2 * NH + j];
    }
}

__global__ void __launch_bounds__(1024, 4)
drl_main(const float* __restrict__ gstatic, const float* __restrict__ gdyn,
         const float* __restrict__ glast, const float* __restrict__ gWhh,
         const float* __restrict__ gbhh, const float* __restrict__ wsb,
         float* __restrict__ out)
{
    __shared__ float s0[2][NN], s1[2][NN], d1[2][NN];
    __shared__ v2f hs2[NH];                // h interleaved over batch: (g0,g1)
    __shared__ float ghs[2][NH3];
    __shared__ float qp[2][NH];
    __shared__ float4 cA[NH];
    __shared__ float4 cP[NH];
    __shared__ float4 cP2[NH];
    __shared__ float2 Mgi[NH3];
    __shared__ float cgi[NH3], bhh[NH3];
    __shared__ float a0v[NH];
    __shared__ float spart[2][NN * 20];    // 16 partials per n, stride 20 (16B-aligned)
    __shared__ float Sw[2][2];
    __shared__ int idxs[2];

    const int t = threadIdx.x;
    const int g = t >> 9;          // batch elem within block
    const int r = t & 511;
    const int b0 = blockIdx.x * 2;

    // ---- stage inputs + coefficients into LDS
    for (int i = t; i < 2 * NN; i += 1024) {
        int gg = i >> 7, n = i & 127, b = b0 + gg;
        s0[gg][n] = gstatic[b * (NF * NN) + n];
        s1[gg][n] = gstatic[b * (NF * NN) + NN + n];
        d1[gg][n] = gdyn[b * (NF * NN) + NN + n];
    }
    for (int i = t; i < 2 * NH; i += 1024) {
        int gg = i >> 8, j = i & 255;
        ((float*)hs2)[2 * j + gg] = glast[(b0 + gg) * NH + j];
    }
    for (int i = t; i < 1536; i += 1024) ((float*)Mgi)[i] = wsb[i];
    if (t < 768) cgi[t] = wsb[1536 + t];
    if (t < 1024) ((float*)cA)[t] = wsb[2304 + t];
    if (t < 256) a0v[t] = wsb[3328 + t];
    if (t < 1024) ((float*)cP)[t] = wsb[3584 + t];
    if (t < 1024) ((float*)cP2)[t] = wsb[70912 + t];
    if (t < 768) bhh[t] = gbhh[t];
    if (t == 0) { idxs[0] = 0; idxs[1] = 0; }
    __syncthreads();

    const float* WaH = wsb + 5376;
    const int jb = t >> 3, kq = t & 7;     // fused-GEMV tiling: 128 rows, 8-way k-split
    const int jb2 = t >> 2, kh = t & 3;    // qp GEMV tiling: 256 rows, 4-way k-split

    // scan tiling: thread owns h-set {hg + 16*hl, hl<16}, n-quad {n0..n0+3} as 2 pairs
    const int ng = r >> 4, hg = r & 15;
    const int n0 = ng * 4;
    v2f sa0, sa1, da, sb0, sb1, db;
    sa0.x = s0[g][n0];     sa0.y = s0[g][n0 + 1];
    sa1.x = s1[g][n0];     sa1.y = s1[g][n0 + 1];
    da.x  = d1[g][n0];     da.y  = d1[g][n0 + 1];
    sb0.x = s0[g][n0 + 2]; sb0.y = s0[g][n0 + 3];
    sb1.x = s1[g][n0 + 2]; sb1.y = s1[g][n0 + 3];
    db.x  = d1[g][n0 + 2]; db.y  = d1[g][n0 + 3];
    float cwsum, vpsum;
    {
        float cw = 0.f, vq = 0.f;
        #pragma unroll 8
        for (int hl = 0; hl < 16; hl++) {
            cw += cA[hg + 16 * hl].w;
            vq += cP[hg + 16 * hl].z;
        }
        cwsum = -0.5f * cw; vpsum = -0.5f * vq;   // = sum(va), sum(vp) over h-set
    }

    // ---- initial gh = W_hh*last_hh + b_hh (768 rows, 8-way k-split, batch-packed)
    {
        v2f acc[6];
        #pragma unroll
        for (int i = 0; i < 6; i++) { acc[i].x = 0.f; acc[i].y = 0.f; }
        const float* wb = gWhh + jb * NH + 4 * kq;
        #pragma unroll 2
        for (int c = 0; c < 8; c++) {
            float4 p01 = *(const float4*)&((float*)hs2)[2 * (32 * c + 4 * kq)];
            float4 p23 = *(const float4*)&((float*)hs2)[2 * (32 * c + 4 * kq) + 4];
            v2f hk0, hk1, hk2, hk3;
            hk0.x = p01.x; hk0.y = p01.y; hk1.x = p01.z; hk1.y = p01.w;
            hk2.x = p23.x; hk2.y = p23.y; hk3.x = p23.z; hk3.y = p23.w;
            #pragma unroll
            for (int p = 0; p < 6; p++) {
                float4 w = *(const float4*)(wb + p * 128 * NH + 32 * c);
                acc[p] = vfma(vsplat(w.x), hk0, vfma(vsplat(w.y), hk1,
                         vfma(vsplat(w.z), hk2, vfma(vsplat(w.w), hk3, acc[p]))));
            }
        }
        #pragma unroll
        for (int p = 0; p < 6; p++) {
            float u0 = acc[p].x, u1 = acc[p].y;
            u0 += __shfl_xor(u0, 1); u0 += __shfl_xor(u0, 2); u0 += __shfl_xor(u0, 4);
            u1 += __shfl_xor(u1, 1); u1 += __shfl_xor(u1, 2); u1 += __shfl_xor(u1, 4);
            if (kq == 0) { int j = jb + 128 * p; ghs[0][j] = u0 + bhh[j]; ghs[1][j] = u1 + bhh[j]; }
        }
    }
    __syncthreads();

    for (int step = 0; step < NN; step++) {
        // ---- P2: GRU elementwise (512 of 1024 threads active)
        if (r < 256) {
            int id = idxs[g];
            float svA = s0[g][id], svB = s1[g][id];
            float2 m0 = Mgi[r], m1 = Mgi[NH + r], m2 = Mgi[2 * NH + r];
            float ir  = fmaf(m0.x, svA, fmaf(m0.y, svB, cgi[r]));
            float iz  = fmaf(m1.x, svA, fmaf(m1.y, svB, cgi[NH + r]));
            float inn = fmaf(m2.x, svA, fmaf(m2.y, svB, cgi[2 * NH + r]));
            float rr = sigm(ir + ghs[g][r]);
            float zz = sigm(iz + ghs[g][NH + r]);
            float nv = tanh_raw(fmaf(rr, ghs[g][2 * NH + r], inn));
            float ho = ((float*)hs2)[2 * r + g];
            ((float*)hs2)[2 * r + g] = fmaf(zz, ho - nv, nv);
        }
        __syncthreads();
        // ---- B: qp = SC*Wa_h*h + a0  (256 rows, 4-way k-split, batch-packed)
        {
            v2f u; u.x = 0.f; u.y = 0.f;
            const float* wq = WaH + jb2 * NH + 4 * kh;
            #pragma unroll 4
            for (int ks = 0; ks < 16; ks++) {
                float4 w  = *(const float4*)(wq + ks * 16);
                float4 p01 = *(const float4*)&((float*)hs2)[2 * (ks * 16 + 4 * kh)];
                float4 p23 = *(const float4*)&((float*)hs2)[2 * (ks * 16 + 4 * kh) + 4];
                v2f hk0, hk1, hk2, hk3;
                hk0.x = p01.x; hk0.y = p01.y; hk1.x = p01.z; hk1.y = p01.w;
                hk2.x = p23.x; hk2.y = p23.y; hk3.x = p23.z; hk3.y = p23.w;
                u = vfma(vsplat(w.x), hk0, vfma(vsplat(w.y), hk1,
                    vfma(vsplat(w.z), hk2, vfma(vsplat(w.w), hk3, u))));
            }
            u.x += __shfl_xor(u.x, 1); u.x += __shfl_xor(u.x, 2);
            u.y += __shfl_xor(u.y, 1); u.y += __shfl_xor(u.y, 2);
            if (kh == 0) { qp[0][jb2] = u.x + a0v[jb2]; qp[1][jb2] = u.y + a0v[jb2]; }
        }
        __syncthreads();
        // ---- C: fused W_hh rows [0,384) GEMV + attention scan (16h x 4n, 4-way rcp)
        {
            v2f at_a = vsplat(cwsum), at_b = vsplat(cwsum);
            v2f g0, g1, g2;
            g0.x = 0.f; g0.y = 0.f; g1.x = 0.f; g1.y = 0.f; g2.x = 0.f; g2.y = 0.f;
            const float* wb = gWhh + jb * NH + 4 * kq;
            #pragma unroll 1
            for (int ks = 0; ks < 8; ks++) {
                float4 w0 = *(const float4*)(wb + 0 * 128 * NH + ks * 32);
                float4 w1 = *(const float4*)(wb + 1 * 128 * NH + ks * 32);
                float4 w2 = *(const float4*)(wb + 2 * 128 * NH + ks * 32);
                #pragma unroll
                for (int u = 0; u < 2; u++) {
                    int h = hg + 16 * (2 * ks + u);
                    float4 c4 = cA[h];
                    float qv = qp[g][h];
                    v2f xa = vfma(vsplat(c4.x), sa0, vfma(vsplat(c4.y), sa1,
                             vfma(vsplat(c4.z), da, vsplat(qv))));
                    v2f xb = vfma(vsplat(c4.x), sb0, vfma(vsplat(c4.y), sb1,
                             vfma(vsplat(c4.z), db, vsplat(qv))));
                    v2f ea, eb;
                    ea.x = fast_exp2(xa.x); ea.y = fast_exp2(xa.y);
                    eb.x = fast_exp2(xb.x); eb.y = fast_exp2(xb.y);
                    v2f ta = ea + 1.0f, tb = eb + 1.0f;
                    float pa = ta.x * ta.y, pb = tb.x * tb.y;
                    float rd = fast_rcp(pa * pb);
                    float m = c4.w * rd;                 // c4.w = -2*va
                    at_a = vfma(vsplat(m * pb), ta.yx, at_a);
                    at_b = vfma(vsplat(m * pa), tb.yx, at_b);
                }
                float4 p01 = *(const float4*)&((float*)hs2)[2 * (ks * 32 + 4 * kq)];
                float4 p23 = *(const float4*)&((float*)hs2)[2 * (ks * 32 + 4 * kq) + 4];
                v2f hk0, hk1, hk2, hk3;
                hk0.x = p01.x; hk0.y = p01.y; hk1.x = p01.z; hk1.y = p01.w;
                hk2.x = p23.x; hk2.y = p23.y; hk3.x = p23.z; hk3.y = p23.w;
                g0 = vfma(vsplat(w0.x), hk0, vfma(vsplat(w0.y), hk1,
                     vfma(vsplat(w0.z), hk2, vfma(vsplat(w0.w), hk3, g0))));
                g1 = vfma(vsplat(w1.x), hk0, vfma(vsplat(w1.y), hk1,
                     vfma(vsplat(w1.z), hk2, vfma(vsplat(w1.w), hk3, g1))));
                g2 = vfma(vsplat(w2.x), hk0, vfma(vsplat(w2.y), hk1,
                     vfma(vsplat(w2.z), hk2, vfma(vsplat(w2.w), hk3, g2))));
            }
            spart[g][(n0 + 0) * 20 + hg] = at_a.x;
            spart[g][(n0 + 1) * 20 + hg] = at_a.y;
            spart[g][(n0 + 2) * 20 + hg] = at_b.x;
            spart[g][(n0 + 3) * 20 + hg] = at_b.y;
            g0.x += __shfl_xor(g0.x, 1); g0.x += __shfl_xor(g0.x, 2); g0.x += __shfl_xor(g0.x, 4);
            g0.y += __shfl_xor(g0.y, 1); g0.y += __shfl_xor(g0.y, 2); g0.y += __shfl_xor(g0.y, 4);
            g1.x += __shfl_xor(g1.x, 1); g1.x += __shfl_xor(g1.x, 2); g1.x += __shfl_xor(g1.x, 4);
            g1.y += __shfl_xor(g1.y, 1); g1.y += __shfl_xor(g1.y, 2); g1.y += __shfl_xor(g1.y, 4);
            g2.x += __shfl_xor(g2.x, 1); g2.x += __shfl_xor(g2.x, 2); g2.x += __shfl_xor(g2.x, 4);
            g2.y += __shfl_xor(g2.y, 1); g2.y += __shfl_xor(g2.y, 2); g2.y += __shfl_xor(g2.y, 4);
            if (kq == 0) {
                ghs[0][jb]       = g0.x + bhh[jb];
                ghs[1][jb]       = g0.y + bhh[jb];
                ghs[0][jb + 128] = g1.x + bhh[jb + 128];
                ghs[1][jb + 128] = g1.y + bhh[jb + 128];
                ghs[0][jb + 256] = g2.x + bhh[jb + 256];
                ghs[1][jb + 256] = g2.y + bhh[jb + 256];
            }
        }
        __syncthreads();
        // ---- P5: sum 16 partials + softmax over n -> weighted sums S0w,S1w
        if (r < 64) {
            int l = r;
            const float* sp0 = &spart[g][l * 20];
            const float* sp1 = &spart[g][(l + 64) * 20];
            float4 q0 = *(const float4*)(sp0), q1 = *(const float4*)(sp0 + 4);
            float4 q2 = *(const float4*)(sp0 + 8), q3 = *(const float4*)(sp0 + 12);
            float v0 = ((q0.x+q0.y)+(q0.z+q0.w)) + ((q1.x+q1.y)+(q1.z+q1.w))
                     + ((q2.x+q2.y)+(q2.z+q2.w)) + ((q3.x+q3.y)+(q3.z+q3.w));
            q0 = *(const float4*)(sp1); q1 = *(const float4*)(sp1 + 4);
            q2 = *(const float4*)(sp1 + 8); q3 = *(const float4*)(sp1 + 12);
            float v1 = ((q0.x+q0.y)+(q0.z+q0.w)) + ((q1.x+q1.y)+(q1.z+q1.w))
                     + ((q2.x+q2.y)+(q2.z+q2.w)) + ((q3.x+q3.y)+(q3.z+q3.w));
            float m = fmaxf(v0, v1);
            #pragma unroll
            for (int o = 32; o; o >>= 1) m = fmaxf(m, __shfl_xor(m, o));
            float e0 = __expf(v0 - m), e1 = __expf(v1 - m);
            float ss = e0 + e1;
            #pragma unroll
            for (int o = 32; o; o >>= 1) ss += __shfl_xor(ss, o);
            float rs = fast_rcp(ss);
            float w0 = e0 * rs, w1 = e1 * rs;
            float t0 = fmaf(w0, s0[g][l], w1 * s0[g][l + 64]);
            float t1 = fmaf(w0, s1[g][l], w1 * s1[g][l + 64]);
            #pragma unroll
            for (int o = 32; o; o >>= 1) { t0 += __shfl_xor(t0, o); t1 += __shfl_xor(t1, o); }
            if (l == 0) { Sw[g][0] = t0; Sw[g][1] = t1; }
        }
        __syncthreads();
        // ---- P7: fused W_hh rows [384,768) GEMV + pointer scan (16h x 4n, 4-way rcp)
        {
            float S0 = Sw[g][0], S1 = Sw[g][1];
            v2f at_a = vsplat(vpsum), at_b = vsplat(vpsum);
            v2f g0, g1, g2;
            g0.x = 0.f; g0.y = 0.f; g1.x = 0.f; g1.y = 0.f; g2.x = 0.f; g2.y = 0.f;
            const float* wb = gWhh + (384 + jb) * NH + 4 * kq;
            #pragma unroll 1
            for (int ks = 0; ks < 8; ks++) {
                float4 w0 = *(const float4*)(wb + 0 * 128 * NH + ks * 32);
                float4 w1 = *(const float4*)(wb + 1 * 128 * NH + ks * 32);
                float4 w2 = *(const float4*)(wb + 2 * 128 * NH + ks * 32);
                #pragma unroll
                for (int u = 0; u < 2; u++) {
                    int h = hg + 16 * (2 * ks + u);
                    float4 c4 = cP[h];
                    float4 c2 = cP2[h];
                    float pc = fmaf(c2.x, S0, fmaf(c2.y, S1, c2.z));
                    v2f xa = vfma(vsplat(c4.x), sa0, vfma(vsplat(c4.y), sa1, vsplat(pc)));
                    v2f xb = vfma(vsplat(c4.x), sb0, vfma(vsplat(c4.y), sb1, vsplat(pc)));
                    v2f ea, eb;
                    ea.x = fast_exp2(xa.x); ea.y = fast_exp2(xa.y);
                    eb.x = fast_exp2(xb.x); eb.y = fast_exp2(xb.y);
                    v2f ta = ea + 1.0f, tb = eb + 1.0f;
                    float pa = ta.x * ta.y, pb = tb.x * tb.y;
                    float rd = fast_rcp(pa * pb);
                    float m = c4.z * rd;                 // c4.z = -2*vp
                    at_a = vfma(vsplat(m * pb), ta.yx, at_a);
                    at_b = vfma(vsplat(m * pa), tb.yx, at_b);
                }
                float4 p01 = *(const float4*)&((float*)hs2)[2 * (ks * 32 + 4 * kq)];
                float4 p23 = *(const float4*)&((float*)hs2)[2 * (ks * 32 + 4 * kq) + 4];
                v2f hk0, hk1, hk2, hk3;
                hk0.x = p01.x; hk0.y = p01.y; hk1.x = p01.z; hk1.y = p01.w;
                hk2.x = p23.x; hk2.y = p23.y; hk3.x = p23.z; hk3.y = p23.w;
                g0 = vfma(vsplat(w0.x), hk0, vfma(vsplat(w0.y), hk1,
                     vfma(vsplat(w0.z), hk2, vfma(vsplat(w0.w), hk3, g0))));
                g1 = vfma(vsplat(w1.x), hk0, vfma(vsplat(w1.y), hk1,
                     vfma(vsplat(w1.z), hk2, vfma(vsplat(w1.w), hk3, g1))));
                g2 = vfma(vsplat(w2.x), hk0, vfma(vsplat(w2.y), hk1,
                     vfma(vsplat(w2.z), hk2, vfma(vsplat(w2.w), hk3, g2))));
            }
            spart[g][(n0 + 0) * 20 + hg] = at_a.x;
            spart[g][(n0 + 1) * 20 + hg] = at_a.y;
            spart[g][(n0 + 2) * 20 + hg] = at_b.x;
            spart[g][(n0 + 3) * 20 + hg] = at_b.y;
            g0.x += __shfl_xor(g0.x, 1); g0.x += __shfl_xor(g0.x, 2); g0.x += __shfl_xor(g0.x, 4);
            g0.y += __shfl_xor(g0.y, 1); g0.y += __shfl_xor(g0.y, 2); g0.y += __shfl_xor(g0.y, 4);
            g1.x += __shfl_xor(g1.x, 1); g1.x += __shfl_xor(g1.x, 2); g1.x += __shfl_xor(g1.x, 4);
            g1.y += __shfl_xor(g1.y, 1); g1.y += __shfl_xor(g1.y, 2); g1.y += __shfl_xor(g1.y, 4);
            g2.x += __shfl_xor(g2.x, 1); g2.x += __shfl_xor(g2.x, 2); g2.x += __shfl_xor(g2.x, 4);
            g2.y += __shfl_xor(g2.y, 1); g2.y += __shfl_xor(g2.y, 2); g2.y += __shfl_xor(g2.y, 4);
            if (kq == 0) {
                ghs[0][384 + jb] = g0.x + bhh[384 + jb];
                ghs[1][384 + jb] = g0.y + bhh[384 + jb];
                ghs[0][512 + jb] = g1.x + bhh[512 + jb];
                ghs[1][512 + jb] = g1.y + bhh[512 + jb];
                ghs[0][640 + jb] = g2.x + bhh[640 + jb];
                ghs[1][640 + jb] = g2.y + bhh[640 + jb];
            }
        }
        __syncthreads();
        // ---- P8: sum 16 partials + softmax + argmax (first-index tiebreak) + outputs
        if (r < 64) {
            int l = r;
            const float* sp0 = &spart[g][l * 20];
            const float* sp1 = &spart[g][(l + 64) * 20];
            float4 q0 = *(const float4*)(sp0), q1 = *(const float4*)(sp0 + 4);
            float4 q2 = *(const float4*)(sp0 + 8), q3 = *(const float4*)(sp0 + 12);
            float v0 = ((q0.x+q0.y)+(q0.z+q0.w)) + ((q1.x+q1.y)+(q1.z+q1.w))
                     + ((q2.x+q2.y)+(q2.z+q2.w)) + ((q3.x+q3.y)+(q3.z+q3.w));
            q0 = *(const float4*)(sp1); q1 = *(const float4*)(sp1 + 4);
            q2 = *(const float4*)(sp1 + 8); q3 = *(const float4*)(sp1 + 12);
            float v1 = ((q0.x+q0.y)+(q0.z+q0.w)) + ((q1.x+q1.y)+(q1.z+q1.w))
                     + ((q2.x+q2.y)+(q2.z+q2.w)) + ((q3.x+q3.y)+(q3.z+q3.w));
            float bv = v0; int bi = l;
            if (v1 > v0) { bv = v1; bi = l + 64; }
            #pragma unroll
            for (int o = 32; o; o >>= 1) {
                float ov = __shfl_xor(bv, o); int oi = __shfl_xor(bi, o);
                if (ov > bv || (ov == bv && oi < bi)) { bv = ov; bi = oi; }
            }
            float e0 = __expf(v0 - bv), e1 = __expf(v1 - bv);
            float ss = e0 + e1;
            #pragma unroll
            for (int o = 32; o; o >>= 1) ss += __shfl_xor(ss, o);
            if (l == 0) {
                idxs[g] = bi;
                int b = b0 + g;
                out[b * NN + step] = (float)bi;
                out[NB * NN + b * NN + step] = -logf(ss);
            }
        }
        __syncthreads();
    }
}

extern "C" void kernel_launch(void* const* d_in, const int* in_sizes, int n_in,
                              void* d_out, int out_size, void* d_ws, size_t ws_size,
                              hipStream_t stream) {
    const float* gstatic = (const float*)d_in[0];
    const float* gdyn    = (const float*)d_in[1];
    const float* glast   = (const float*)d_in[2];
    const float* Ws      = (const float*)d_in[3];
    const float* bs      = (const float*)d_in[4];
    const float* Wd      = (const float*)d_in[5];
    const float* bd      = (const float*)d_in[6];
    const float* Wdec    = (const float*)d_in[7];
    const float* bdec    = (const float*)d_in[8];
    const float* W_ih    = (const float*)d_in[9];
    const float* W_hh    = (const float*)d_in[10];
    const float* b_ih    = (const float*)d_in[11];
    const float* b_hh    = (const float*)d_in[12];
    const float* Wa      = (const float*)d_in[13];
    const float* va      = (const float*)d_in[14];
    const float* Wp      = (const float*)d_in[15];
    const float* vp      = (const float*)d_in[16];
    float* outp = (float*)d_out;
    float* wsb  = (float*)d_ws;

    precompute_kernel<<<267, 256, 0, stream>>>(Ws, bs, Wd, bd, Wdec, bdec,
                                               W_ih, b_ih, Wa, va, Wp, vp, wsb);
    drl_main<<<256, 1024, 0, stream>>>(gstatic, gdyn, glast, W_hh, b_hh, wsb, outp);
}

// Round 8
// 1964.969 us; speedup vs baseline: 3.7649x; 1.0564x over previous
//
#include <hip/hip_runtime.h>
#include <math.h>

// DRL4TSP decode: B=512, F=2, N=128, H=256, 128 steps.
// R8: move GEMV reductions out of the L2-streaming phases. C/P7 write raw
// 8-way-k partials to a padded LDS buffer (stride 20, conflict-free); the
// 896 idle threads in P5/P8 reduce them into ghs (+bias). Removes 36 shfl +
// 6 cond-writes per streaming phase per thread. P5 softmax: no max-subtract
// (|logit|<=10), single fused butterfly over (Se, Se*s0, Se*s1). P8: argmax
// butterfly carries unnormalized Se^v; logp = bv - log(Se^v).

#define NB 512
#define NF 2
#define NN 128
#define NH 256
#define NH3 768
#define SC 2.8853900817779268f   // 2*log2(e): folds tanh doubling + exp->exp2

typedef float v2f __attribute__((ext_vector_type(2)));

__device__ __forceinline__ float fast_rcp(float x) { return __builtin_amdgcn_rcpf(x); }
__device__ __forceinline__ float fast_exp2(float x) { return __builtin_amdgcn_exp2f(x); }
__device__ __forceinline__ float sigm(float x) { return fast_rcp(1.0f + __expf(-x)); }
__device__ __forceinline__ float tanh_raw(float x) { return 1.0f - 2.0f * fast_rcp(1.0f + fast_exp2(SC * x)); }
__device__ __forceinline__ v2f vsplat(float a) { v2f r; r.x = a; r.y = a; return r; }
__device__ __forceinline__ v2f vfma(v2f a, v2f b, v2f c) { return __builtin_elementwise_fma(a, b, c); }

// ws layout (floats):
//   0     : Mgi[768] float2   (W_ih·Wdec, 2 cols interleaved)   [unscaled]
//   1536  : cgi[768]          (W_ih·bdec + b_ih)                [unscaled]
//   2304  : cA[256] float4    (SC*A_s0, SC*A_s1, SC*A_d1, -2*va)
//   3328  : a0[256]           (SC*(Wa_s·bs + Wa_d·(20*Wd0+bd)))
//   3584  : cP[256] float4    (SC*P_s0, SC*P_s1, -2*vp, 0)
//   5376  : WaH[256*256]      (SC*Wa[:,2H:3H] row-major)
//   70912 : cP2[256] float4   (SC*PC0, SC*PC1, SC*pb, 0)

__global__ void precompute_kernel(const float* __restrict__ Ws, const float* __restrict__ bs,
                                  const float* __restrict__ Wd, const float* __restrict__ bd,
                                  const float* __restrict__ Wdec, const float* __restrict__ bdec,
                                  const float* __restrict__ W_ih, const float* __restrict__ b_ih,
                                  const float* __restrict__ Wa, const float* __restrict__ va,
                                  const float* __restrict__ Wp, const float* __restrict__ vp,
                                  float* __restrict__ ws)
{
    int tid = blockIdx.x * blockDim.x + threadIdx.x;
    if (tid < 768) {                              // Mgi
        int j = tid; const float* wr = &W_ih[j * NH];
        float m0 = 0.f, m1 = 0.f;
        for (int k = 0; k < NH; k++) { float w = wr[k]; m0 = fmaf(w, Wdec[2*k], m0); m1 = fmaf(w, Wdec[2*k+1], m1); }
        ws[2*j] = m0; ws[2*j+1] = m1;
    } else if (tid < 1536) {                      // cgi
        int j = tid - 768; const float* wr = &W_ih[j * NH];
        float c = b_ih[j];
        for (int k = 0; k < NH; k++) c = fmaf(wr[k], bdec[k], c);
        ws[1536 + j] = c;
    } else if (tid < 1792) {                      // cA (SC-scaled; .w = -2*va)
        int h = tid - 1536; const float* war = &Wa[h * NH3];
        float as0 = 0.f, as1 = 0.f, ad1 = 0.f;
        for (int k = 0; k < NH; k++) {
            float w = war[k];
            as0 = fmaf(w, Ws[2*k], as0); as1 = fmaf(w, Ws[2*k+1], as1);
            ad1 = fmaf(war[NH + k], Wd[2*k+1], ad1);
        }
        float4 v = make_float4(SC*as0, SC*as1, SC*ad1, -2.0f*va[h]);
        ((float4*)(ws + 2304))[h] = v;
    } else if (tid < 2048) {                      // a0 (SC)
        int h = tid - 1792; const float* war = &Wa[h * NH3];
        float a = 0.f;
        for (int k = 0; k < NH; k++) {
            a = fmaf(war[k], bs[k], a);
            a = fmaf(war[NH + k], fmaf(20.0f, Wd[2*k], bd[k]), a);
        }
        ws[3328 + h] = SC * a;
    } else if (tid < 2304) {                      // cP (SC-scaled; .z = -2*vp)
        int h = tid - 2048; const float* wpr = &Wp[h * 2 * NH];
        float p0 = 0.f, p1 = 0.f;
        for (int k = 0; k < NH; k++) { float w = wpr[k]; p0 = fmaf(w, Ws[2*k], p0); p1 = fmaf(w, Ws[2*k+1], p1); }
        float4 v = make_float4(SC*p0, SC*p1, -2.0f*vp[h], 0.f);
        ((float4*)(ws + 3584))[h] = v;
    } else if (tid < 2560) {                      // cP2: SC*(PC0, PC1, pb)
        int h = tid - 2304;
        const float* wps = &Wp[h * 2 * NH];
        const float* wpc = wps + NH;
        float p0 = 0.f, p1 = 0.f, pb = 0.f;
        for (int k = 0; k < NH; k++) {
            p0 = fmaf(wpc[k], Ws[2*k], p0);
            p1 = fmaf(wpc[k], Ws[2*k+1], p1);
            pb = fmaf(wps[k] + wpc[k], bs[k], pb);
        }
        float4 v = make_float4(SC*p0, SC*p1, SC*pb, 0.f);
        ((float4*)(ws + 70912))[h] = v;
    } else if (tid < 2560 + 65536) {              // WaH pack (SC)
        int m = tid - 2560; int i = m >> 8, j = m & 255;
        ws[5376 + m] = SC * Wa[i * NH3 + 2 * NH + j];
    }
}

__global__ void __launch_bounds__(1024, 4)
drl_main(const float* __restrict__ gstatic, const float* __restrict__ gdyn,
         const float* __restrict__ glast, const float* __restrict__ gWhh,
         const float* __restrict__ gbhh, const float* __restrict__ wsb,
         float* __restrict__ out)
{
    __shared__ float s0[2][NN], s1[2][NN], d1[2][NN];
    __shared__ v2f hs2[NH];                // h interleaved over batch: (g0,g1)
    __shared__ float ghs[2][NH3];
    __shared__ float qp[2][NH];
    __shared__ float4 cA[NH];
    __shared__ float4 cP[NH];
    __shared__ float4 cP2[NH];
    __shared__ float2 Mgi[NH3];
    __shared__ float cgi[NH3], bhh[NH3];
    __shared__ float a0v[NH];
    __shared__ float spart[2][NN * 20];    // 16 scan partials per n, stride 20
    __shared__ float gpart[384 * 20];      // GEMV partials: [lr][kq*2+g], stride 20
    __shared__ float Sw[2][2];
    __shared__ int idxs[2];

    const int t = threadIdx.x;
    const int g = t >> 9;          // batch elem within block
    const int r = t & 511;
    const int b0 = blockIdx.x * 2;

    // ---- stage inputs + coefficients into LDS
    for (int i = t; i < 2 * NN; i += 1024) {
        int gg = i >> 7, n = i & 127, b = b0 + gg;
        s0[gg][n] = gstatic[b * (NF * NN) + n];
        s1[gg][n] = gstatic[b * (NF * NN) + NN + n];
        d1[gg][n] = gdyn[b * (NF * NN) + NN + n];
    }
    for (int i = t; i < 2 * NH; i += 1024) {
        int gg = i >> 8, j = i & 255;
        ((float*)hs2)[2 * j + gg] = glast[(b0 + gg) * NH + j];
    }
    for (int i = t; i < 1536; i += 1024) ((float*)Mgi)[i] = wsb[i];
    if (t < 768) cgi[t] = wsb[1536 + t];
    if (t < 1024) ((float*)cA)[t] = wsb[2304 + t];
    if (t < 256) a0v[t] = wsb[3328 + t];
    if (t < 1024) ((float*)cP)[t] = wsb[3584 + t];
    if (t < 1024) ((float*)cP2)[t] = wsb[70912 + t];
    if (t < 768) bhh[t] = gbhh[t];
    if (t == 0) { idxs[0] = 0; idxs[1] = 0; }
    __syncthreads();

    const float* WaH = wsb + 5376;
    const int jb = t >> 3, kq = t & 7;     // fused-GEMV tiling: 128 rows, 8-way k-split
    const int jb2 = t >> 2, kh = t & 3;    // qp GEMV tiling: 256 rows, 4-way k-split

    // scan tiling: thread owns h-set {hg + 16*hl, hl<16}, n-quad {n0..n0+3} as 2 pairs
    const int ng = r >> 4, hg = r & 15;
    const int n0 = ng * 4;
    v2f sa0, sa1, da, sb0, sb1, db;
    sa0.x = s0[g][n0];     sa0.y = s0[g][n0 + 1];
    sa1.x = s1[g][n0];     sa1.y = s1[g][n0 + 1];
    da.x  = d1[g][n0];     da.y  = d1[g][n0 + 1];
    sb0.x = s0[g][n0 + 2]; sb0.y = s0[g][n0 + 3];
    sb1.x = s1[g][n0 + 2]; sb1.y = s1[g][n0 + 3];
    db.x  = d1[g][n0 + 2]; db.y  = d1[g][n0 + 3];
    float cwsum, vpsum;
    {
        float cw = 0.f, vq = 0.f;
        #pragma unroll 8
        for (int hl = 0; hl < 16; hl++) {
            cw += cA[hg + 16 * hl].w;
            vq += cP[hg + 16 * hl].z;
        }
        cwsum = -0.5f * cw; vpsum = -0.5f * vq;   // = sum(va), sum(vp) over h-set
    }

    // ---- initial gh = W_hh*last_hh + b_hh (768 rows, 8-way k-split, batch-packed)
    {
        v2f acc[6];
        #pragma unroll
        for (int i = 0; i < 6; i++) { acc[i].x = 0.f; acc[i].y = 0.f; }
        const float* wb = gWhh + jb * NH + 4 * kq;
        #pragma unroll 2
        for (int c = 0; c < 8; c++) {
            float4 p01 = *(const float4*)&((float*)hs2)[2 * (32 * c + 4 * kq)];
            float4 p23 = *(const float4*)&((float*)hs2)[2 * (32 * c + 4 * kq) + 4];
            v2f hk0, hk1, hk2, hk3;
            hk0.x = p01.x; hk0.y = p01.y; hk1.x = p01.z; hk1.y = p01.w;
            hk2.x = p23.x; hk2.y = p23.y; hk3.x = p23.z; hk3.y = p23.w;
            #pragma unroll
            for (int p = 0; p < 6; p++) {
                float4 w = *(const float4*)(wb + p * 128 * NH + 32 * c);
                acc[p] = vfma(vsplat(w.x), hk0, vfma(vsplat(w.y), hk1,
                         vfma(vsplat(w.z), hk2, vfma(vsplat(w.w), hk3, acc[p]))));
            }
        }
        #pragma unroll
        for (int p = 0; p < 6; p++) {
            float u0 = acc[p].x, u1 = acc[p].y;
            u0 += __shfl_xor(u0, 1); u0 += __shfl_xor(u0, 2); u0 += __shfl_xor(u0, 4);
            u1 += __shfl_xor(u1, 1); u1 += __shfl_xor(u1, 2); u1 += __shfl_xor(u1, 4);
            if (kq == 0) { int j = jb + 128 * p; ghs[0][j] = u0 + bhh[j]; ghs[1][j] = u1 + bhh[j]; }
        }
    }
    __syncthreads();

    for (int step = 0; step < NN; step++) {
        // ---- P2: GRU elementwise (512 of 1024 threads active)
        if (r < 256) {
            int id = idxs[g];
            float svA = s0[g][id], svB = s1[g][id];
            float2 m0 = Mgi[r], m1 = Mgi[NH + r], m2 = Mgi[2 * NH + r];
            float ir  = fmaf(m0.x, svA, fmaf(m0.y, svB, cgi[r]));
            float iz  = fmaf(m1.x, svA, fmaf(m1.y, svB, cgi[NH + r]));
            float inn = fmaf(m2.x, svA, fmaf(m2.y, svB, cgi[2 * NH + r]));
            float rr = sigm(ir + ghs[g][r]);
            float zz = sigm(iz + ghs[g][NH + r]);
            float nv = tanh_raw(fmaf(rr, ghs[g][2 * NH + r], inn));
            float ho = ((float*)hs2)[2 * r + g];
            ((float*)hs2)[2 * r + g] = fmaf(zz, ho - nv, nv);
        }
        __syncthreads();
        // ---- B: qp = SC*Wa_h*h + a0  (256 rows, 4-way k-split, batch-packed)
        {
            v2f u; u.x = 0.f; u.y = 0.f;
            const float* wq = WaH + jb2 * NH + 4 * kh;
            #pragma unroll 4
            for (int ks = 0; ks < 16; ks++) {
                float4 w  = *(const float4*)(wq + ks * 16);
                float4 p01 = *(const float4*)&((float*)hs2)[2 * (ks * 16 + 4 * kh)];
                float4 p23 = *(const float4*)&((float*)hs2)[2 * (ks * 16 + 4 * kh) + 4];
                v2f hk0, hk1, hk2, hk3;
                hk0.x = p01.x; hk0.y = p01.y; hk1.x = p01.z; hk1.y = p01.w;
                hk2.x = p23.x; hk2.y = p23.y; hk3.x = p23.z; hk3.y = p23.w;
                u = vfma(vsplat(w.x), hk0, vfma(vsplat(w.y), hk1,
                    vfma(vsplat(w.z), hk2, vfma(vsplat(w.w), hk3, u))));
            }
            u.x += __shfl_xor(u.x, 1); u.x += __shfl_xor(u.x, 2);
            u.y += __shfl_xor(u.y, 1); u.y += __shfl_xor(u.y, 2);
            if (kh == 0) { qp[0][jb2] = u.x + a0v[jb2]; qp[1][jb2] = u.y + a0v[jb2]; }
        }
        __syncthreads();
        // ---- C: fused W_hh rows [0,384) GEMV + attention scan; raw partials to gpart
        {
            v2f at_a = vsplat(cwsum), at_b = vsplat(cwsum);
            v2f g0, g1, g2;
            g0.x = 0.f; g0.y = 0.f; g1.x = 0.f; g1.y = 0.f; g2.x = 0.f; g2.y = 0.f;
            const float* wb = gWhh + jb * NH + 4 * kq;
            #pragma unroll 1
            for (int ks = 0; ks < 8; ks++) {
                float4 w0 = *(const float4*)(wb + 0 * 128 * NH + ks * 32);
                float4 w1 = *(const float4*)(wb + 1 * 128 * NH + ks * 32);
                float4 w2 = *(const float4*)(wb + 2 * 128 * NH + ks * 32);
                #pragma unroll
                for (int u = 0; u < 2; u++) {
                    int h = hg + 16 * (2 * ks + u);
                    float4 c4 = cA[h];
                    float qv = qp[g][h];
                    v2f xa = vfma(vsplat(c4.x), sa0, vfma(vsplat(c4.y), sa1,
                             vfma(vsplat(c4.z), da, vsplat(qv))));
                    v2f xb = vfma(vsplat(c4.x), sb0, vfma(vsplat(c4.y), sb1,
                             vfma(vsplat(c4.z), db, vsplat(qv))));
                    v2f ea, eb;
                    ea.x = fast_exp2(xa.x); ea.y = fast_exp2(xa.y);
                    eb.x = fast_exp2(xb.x); eb.y = fast_exp2(xb.y);
                    v2f ta = ea + 1.0f, tb = eb + 1.0f;
                    float pa = ta.x * ta.y, pb = tb.x * tb.y;
                    float rd = fast_rcp(pa * pb);
                    float m = c4.w * rd;                 // c4.w = -2*va
                    at_a = vfma(vsplat(m * pb), ta.yx, at_a);
                    at_b = vfma(vsplat(m * pa), tb.yx, at_b);
                }
                float4 p01 = *(const float4*)&((float*)hs2)[2 * (ks * 32 + 4 * kq)];
                float4 p23 = *(const float4*)&((float*)hs2)[2 * (ks * 32 + 4 * kq) + 4];
                v2f hk0, hk1, hk2, hk3;
                hk0.x = p01.x; hk0.y = p01.y; hk1.x = p01.z; hk1.y = p01.w;
                hk2.x = p23.x; hk2.y = p23.y; hk3.x = p23.z; hk3.y = p23.w;
                g0 = vfma(vsplat(w0.x), hk0, vfma(vsplat(w0.y), hk1,
                     vfma(vsplat(w0.z), hk2, vfma(vsplat(w0.w), hk3, g0))));
                g1 = vfma(vsplat(w1.x), hk0, vfma(vsplat(w1.y), hk1,
                     vfma(vsplat(w1.z), hk2, vfma(vsplat(w1.w), hk3, g1))));
                g2 = vfma(vsplat(w2.x), hk0, vfma(vsplat(w2.y), hk1,
                     vfma(vsplat(w2.z), hk2, vfma(vsplat(w2.w), hk3, g2))));
            }
            spart[g][(n0 + 0) * 20 + hg] = at_a.x;
            spart[g][(n0 + 1) * 20 + hg] = at_a.y;
            spart[g][(n0 + 2) * 20 + hg] = at_b.x;
            spart[g][(n0 + 3) * 20 + hg] = at_b.y;
            *(v2f*)&gpart[(jb      ) * 20 + (kq << 1)] = g0;
            *(v2f*)&gpart[(jb + 128) * 20 + (kq << 1)] = g1;
            *(v2f*)&gpart[(jb + 256) * 20 + (kq << 1)] = g2;
        }
        __syncthreads();
        // ---- P5: ghs[0,384) reduction (idle threads) + softmax (fused butterfly)
        {
            int v = t - 64;
            if (t >= 64 && v < 384) {
                const float* gp = &gpart[v * 20];
                float4 q0 = *(const float4*)(gp);
                float4 q1 = *(const float4*)(gp + 4);
                float4 q2 = *(const float4*)(gp + 8);
                float4 q3 = *(const float4*)(gp + 12);
                float sg0 = ((q0.x + q0.z) + (q1.x + q1.z)) + ((q2.x + q2.z) + (q3.x + q3.z));
                float sg1 = ((q0.y + q0.w) + (q1.y + q1.w)) + ((q2.y + q2.w) + (q3.y + q3.w));
                ghs[0][v] = sg0 + bhh[v];
                ghs[1][v] = sg1 + bhh[v];
            }
            if (r < 64) {
                int l = r;
                const float* sp0 = &spart[g][l * 20];
                const float* sp1 = &spart[g][(l + 64) * 20];
                float4 q0 = *(const float4*)(sp0), q1 = *(const float4*)(sp0 + 4);
                float4 q2 = *(const float4*)(sp0 + 8), q3 = *(const float4*)(sp0 + 12);
                float v0 = ((q0.x+q0.y)+(q0.z+q0.w)) + ((q1.x+q1.y)+(q1.z+q1.w))
                         + ((q2.x+q2.y)+(q2.z+q2.w)) + ((q3.x+q3.y)+(q3.z+q3.w));
                q0 = *(const float4*)(sp1); q1 = *(const float4*)(sp1 + 4);
                q2 = *(const float4*)(sp1 + 8); q3 = *(const float4*)(sp1 + 12);
                float v1 = ((q0.x+q0.y)+(q0.z+q0.w)) + ((q1.x+q1.y)+(q1.z+q1.w))
                         + ((q2.x+q2.y)+(q2.z+q2.w)) + ((q3.x+q3.y)+(q3.z+q3.w));
                // |logits| <= sum|va| ~ 10 -> exp safe without max-subtract
                float e0 = __expf(v0), e1 = __expf(v1);
                float aa = e0 + e1;
                float bb = fmaf(e0, s0[g][l], e1 * s0[g][l + 64]);
                float cc = fmaf(e0, s1[g][l], e1 * s1[g][l + 64]);
                #pragma unroll
                for (int o = 32; o; o >>= 1) {
                    aa += __shfl_xor(aa, o);
                    bb += __shfl_xor(bb, o);
                    cc += __shfl_xor(cc, o);
                }
                if (l == 0) {
                    float rs = fast_rcp(aa);
                    Sw[g][0] = bb * rs; Sw[g][1] = cc * rs;
                }
            }
        }
        __syncthreads();
        // ---- P7: fused W_hh rows [384,768) GEMV + pointer scan; partials to gpart
        {
            float S0 = Sw[g][0], S1 = Sw[g][1];
            v2f at_a = vsplat(vpsum), at_b = vsplat(vpsum);
            v2f g0, g1, g2;
            g0.x = 0.f; g0.y = 0.f; g1.x = 0.f; g1.y = 0.f; g2.x = 0.f; g2.y = 0.f;
            const float* wb = gWhh + (384 + jb) * NH + 4 * kq;
            #pragma unroll 1
            for (int ks = 0; ks < 8; ks++) {
                float4 w0 = *(const float4*)(wb + 0 * 128 * NH + ks * 32);
                float4 w1 = *(const float4*)(wb + 1 * 128 * NH + ks * 32);
                float4 w2 = *(const float4*)(wb + 2 * 128 * NH + ks * 32);
                #pragma unroll
                for (int u = 0; u < 2; u++) {
                    int h = hg + 16 * (2 * ks + u);
                    float4 c4 = cP[h];
                    float4 c2 = cP2[h];
                    float pc = fmaf(c2.x, S0, fmaf(c2.y, S1, c2.z));
                    v2f xa = vfma(vsplat(c4.x), sa0, vfma(vsplat(c4.y), sa1, vsplat(pc)));
                    v2f xb = vfma(vsplat(c4.x), sb0, vfma(vsplat(c4.y), sb1, vsplat(pc)));
                    v2f ea, eb;
                    ea.x = fast_exp2(xa.x); ea.y = fast_exp2(xa.y);
                    eb.x = fast_exp2(xb.x); eb.y = fast_exp2(xb.y);
                    v2f ta = ea + 1.0f, tb = eb + 1.0f;
                    float pa = ta.x * ta.y, pb = tb.x * tb.y;
                    float rd = fast_rcp(pa * pb);
                    float m = c4.z * rd;                 // c4.z = -2*vp
                    at_a = vfma(vsplat(m * pb), ta.yx, at_a);
                    at_b = vfma(vsplat(m * pa), tb.yx, at_b);
                }
                float4 p01 = *(const float4*)&((float*)hs2)[2 * (ks * 32 + 4 * kq)];
                float4 p23 = *(const float4*)&((float*)hs2)[2 * (ks * 32 + 4 * kq) + 4];
                v2f hk0, hk1, hk2, hk3;
                hk0.x = p01.x; hk0.y = p01.y; hk1.x = p01.z; hk1.y = p01.w;
                hk2.x = p23.x; hk2.y = p23.y; hk3.x = p23.z; hk3.y = p23.w;
                g0 = vfma(vsplat(w0.x), hk0, vfma(vsplat(w0.y), hk1,
                     vfma(vsplat(w0.z), hk2, vfma(vsplat(w0.w), hk3, g0))));
                g1 = vfma(vsplat(w1.x), hk0, vfma(vsplat(w1.y), hk1,
                     vfma(vsplat(w1.z), hk2, vfma(vsplat(w1.w), hk3, g1))));
                g2 = vfma(vsplat(w2.x), hk0, vfma(vsplat(w2.y), hk1,
                     vfma(vsplat(w2.z), hk2, vfma(vsplat(w2.w), hk3, g2))));
            }
            spart[g][(n0 + 0) * 20 + hg] = at_a.x;
            spart[g][(n0 + 1) * 20 + hg] = at_a.y;
            spart[g][(n0 + 2) * 20 + hg] = at_b.x;
            spart[g][(n0 + 3) * 20 + hg] = at_b.y;
            *(v2f*)&gpart[(jb      ) * 20 + (kq << 1)] = g0;
            *(v2f*)&gpart[(jb + 128) * 20 + (kq << 1)] = g1;
            *(v2f*)&gpart[(jb + 256) * 20 + (kq << 1)] = g2;
        }
        __syncthreads();
        // ---- P8: ghs[384,768) reduction (idle threads) + argmax (fused butterfly)
        {
            int v = t - 64;
            if (t >= 64 && v < 384) {
                const float* gp = &gpart[v * 20];
                float4 q0 = *(const float4*)(gp);
                float4 q1 = *(const float4*)(gp + 4);
                float4 q2 = *(const float4*)(gp + 8);
                float4 q3 = *(const float4*)(gp + 12);
                float sg0 = ((q0.x + q0.z) + (q1.x + q1.z)) + ((q2.x + q2.z) + (q3.x + q3.z));
                float sg1 = ((q0.y + q0.w) + (q1.y + q1.w)) + ((q2.y + q2.w) + (q3.y + q3.w));
                ghs[0][384 + v] = sg0 + bhh[384 + v];
                ghs[1][384 + v] = sg1 + bhh[384 + v];
            }
            if (r < 64) {
                int l = r;
                const float* sp0 = &spart[g][l * 20];
                const float* sp1 = &spart[g][(l + 64) * 20];
                float4 q0 = *(const float4*)(sp0), q1 = *(const float4*)(sp0 + 4);
                float4 q2 = *(const float4*)(sp0 + 8), q3 = *(const float4*)(sp0 + 12);
                float v0 = ((q0.x+q0.y)+(q0.z+q0.w)) + ((q1.x+q1.y)+(q1.z+q1.w))
                         + ((q2.x+q2.y)+(q2.z+q2.w)) + ((q3.x+q3.y)+(q3.z+q3.w));
                q0 = *(const float4*)(sp1); q1 = *(const float4*)(sp1 + 4);
                q2 = *(const float4*)(sp1 + 8); q3 = *(const float4*)(sp1 + 12);
                float v1 = ((q0.x+q0.y)+(q0.z+q0.w)) + ((q1.x+q1.y)+(q1.z+q1.w))
                         + ((q2.x+q2.y)+(q2.z+q2.w)) + ((q3.x+q3.y)+(q3.z+q3.w));
                float bv = v0; int bi = l;
                if (v1 > v0) { bv = v1; bi = l + 64; }
                float es = __expf(v0) + __expf(v1);    // unnormalized; |v| <= ~10
                #pragma unroll
                for (int o = 32; o; o >>= 1) {
                    float ov = __shfl_xor(bv, o); int oi = __shfl_xor(bi, o);
                    es += __shfl_xor(es, o);
                    if (ov > bv || (ov == bv && oi < bi)) { bv = ov; bi = oi; }
                }
                if (l == 0) {
                    idxs[g] = bi;
                    int b = b0 + g;
                    out[b * NN + step] = (float)bi;
                    out[NB * NN + b * NN + step] = bv - logf(es);  // = -log(sum exp(v-bv))
                }
            }
        }
        __syncthreads();
    }
}

extern "C" void kernel_launch(void* const* d_in, const int* in_sizes, int n_in,
                              void* d_out, int out_size, void* d_ws, size_t ws_size,
                              hipStream_t stream) {
    const float* gstatic = (const float*)d_in[0];
    const float* gdyn    = (const float*)d_in[1];
    const float* glast   = (const float*)d_in[2];
    const float* Ws      = (const float*)d_in[3];
    const float* bs      = (const float*)d_in[4];
    const float* Wd      = (const float*)d_in[5];
    const float* bd      = (const float*)d_in[6];
    const float* Wdec    = (const float*)d_in[7];
    const float* bdec    = (const float*)d_in[8];
    const float* W_ih    = (const float*)d_in[9];
    const float* W_hh    = (const float*)d_in[10];
    const float* b_ih    = (const float*)d_in[11];
    const float* b_hh    = (const float*)d_in[12];
    const float* Wa      = (const float*)d_in[13];
    const float* va      = (const float*)d_in[14];
    const float* Wp      = (const float*)d_in[15];
    const float* vp      = (const float*)d_in[16];
    float* outp = (float*)d_out;
    float* wsb  = (float*)d_ws;

    precompute_kernel<<<267, 256, 0, stream>>>(Ws, bs, Wd, bd, Wdec, bdec,
                                               W_ih, b_ih, Wa, va, Wp, vp, wsb);
    drl_main<<<256, 1024, 0, stream>>>(gstatic, gdyn, glast, W_hh, b_hh, wsb, outp);
}